// Round 2
// baseline (403.927 us; speedup 1.0000x reference)
//
#include <hip/hip_runtime.h>
#include <math.h>

#define NIx 32
#define NOx 2
#define NUx 10
#define NHx 1024
#define NBx 16384
#define MIx 138
#define EPSQ 1e-4f
#define BNEPS 1e-5f
#define ITERS 30
#define SLOPE 0.2f
#define SIGMA_C 0.1f

// workspace layout (float offsets). Max = 174400 floats = 697.6 KB (< proven 723 KB).
#define QM_OFF 0        // 120 (pad 128)
#define G_OFF 128       // 144 x 12 -> 1856
#define H_OFF 1856      // 144 (pad 2048)
#define P2_OFF 2048     // 16 bufs x 20 (sum[10],sq[10]) = 320 (pad 2368)
#define P1S_OFF 2368    // 4 bufs x 1024 col-sums
#define P1Q_OFF 6464    // 4 bufs x 1024 col-sumsq -> 10560
#define PRAW_OFF 10560  // 16384 x 10 -> 174400
// memset zeroes [P2_OFF, P1Q_OFF+4096) = floats 2048..10560

__device__ __forceinline__ float frcp(float x){ return __builtin_amdgcn_rcpf(x); }
__device__ __forceinline__ float frsq(float x){ return __builtin_amdgcn_rsqf(x); }
__device__ __forceinline__ float lrelu(float x){ return x > 0.0f ? x : SLOPE * x; }

// packed fp32 helpers. NOTE (round-1 measurement): v_pk_*_f32 is issue-NEUTRAL on
// gfx950 (implied instr count matches 2x scalar; FP32 spec peak = scalar rate).
// Kept because it is not worse and the pairing structure organizes the code.
typedef float v2f __attribute__((ext_vector_type(2)));
__device__ __forceinline__ v2f make2(float a, float b){ v2f r; r.x = a; r.y = b; return r; }
__device__ __forceinline__ v2f splat2(float a){ v2f r; r.x = a; r.y = a; return r; }
__device__ __forceinline__ v2f pkfma(v2f a, v2f b, v2f c){ return __builtin_elementwise_fma(a, b, c); }
__device__ __forceinline__ v2f pkmax(v2f a, v2f b){ return __builtin_elementwise_max(a, b); }

// ---- DPP cross-lane reductions (VALU, no LDS pipe) ----
template<int CTRL>
__device__ __forceinline__ float dpp_mov(float x){
    int y = __builtin_amdgcn_update_dpp(0, __float_as_int(x), CTRL, 0xF, 0xF, true);
    return __int_as_float(y);
}
// 8-lane all-reduce: xor1 (quad_perm[1,0,3,2]), xor2 (quad_perm[2,3,0,1]),
// then row_half_mirror (0x141: i -> 7-i within each 8 = xor-7) closes the group.
__device__ __forceinline__ float red8_add(float x){
    x += dpp_mov<0xB1>(x);
    x += dpp_mov<0x4E>(x);
    x += dpp_mov<0x141>(x);
    return x;
}
__device__ __forceinline__ float red8_max(float x){
    x = fmaxf(x, dpp_mov<0xB1>(x));
    x = fmaxf(x, dpp_mov<0x4E>(x));
    x = fmaxf(x, dpp_mov<0x141>(x));
    return x;
}

// ---------- merged: blocks 0..511 BN1-stats, block 512 QP-build (independent work) ----------
__global__ __launch_bounds__(256) void k_buildstats(const float* L, const float* LP, const float* LR,
                                                    const float* A, const float* Bm,
                                                    const float* u0, const float* s0,
                                                    const float* x, const float* w1, const float* b1,
                                                    float* ws){
    __shared__ float sL[1024], sLP[1024], sA[1024], sQ[1024], sP[1024];
    __shared__ float sPow[4][64];
    __shared__ float sBh[128*10];
    __shared__ float sQB[128*10];
    __shared__ float sR[3];
    int t = threadIdx.x;
    if (blockIdx.x < 512){
        // ---- BN1 stats path: partial col sum/sumsq into 4 spread buffers ----
        int rb = blockIdx.x >> 2;        // 128 row-groups of 128 rows
        int cb = blockIdx.x & 3;         // 4 col-groups of 256 cols
        int c = cb * 256 + t;
        const float4* wg4 = (const float4*)(w1 + (size_t)c * 32);
        float4 wr[8];
        #pragma unroll
        for (int q = 0; q < 8; ++q) wr[q] = wg4[q];
        float bc = b1[c];
        int r0 = rb * 128;
        float sum = 0.0f, sq = 0.0f;
        #pragma unroll 2
        for (int r = 0; r < 128; ++r){
            // x-row address is wave-uniform: force SGPR base -> s_load (scalar pipe),
            // same trick that paid off in k_fc2 round 1.
            int ro = __builtin_amdgcn_readfirstlane((r0 + r) * 32);
            const float4* xr4 = (const float4*)(x + ro);
            float a0 = 0, a1 = 0, a2 = 0, a3 = 0;
            #pragma unroll
            for (int q = 0; q < 8; ++q){
                float4 v = xr4[q];
                a0 = fmaf(v.x, wr[q].x, a0);
                a1 = fmaf(v.y, wr[q].y, a1);
                a2 = fmaf(v.z, wr[q].z, a2);
                a3 = fmaf(v.w, wr[q].w, a3);
            }
            float h = lrelu((a0 + a1) + (a2 + a3) + bc);
            sum += h; sq = fmaf(h, h, sq);
        }
        int buf = (rb & 3) * 1024 + c;
        atomicAdd(&ws[P1S_OFF + buf], sum);
        atomicAdd(&ws[P1Q_OFF + buf], sq);
        return;
    }
    // ---- QP build path (single block) ----
    for (int idx = t; idx < 1024; idx += 256){
        int i = idx >> 5, j = idx & 31;
        sL[idx]  = (j <= i) ? L[idx]  : 0.0f;
        sLP[idx] = (j <= i) ? LP[idx] : 0.0f;
        sA[idx]  = A[idx];
    }
    if (t < 64) sPow[0][t] = Bm[t];
    if (t == 0){
        float a = LR[0], b = LR[2], c = LR[3];   // tril: [[a,0],[b,c]]
        sR[0] = a*a + EPSQ; sR[1] = a*b; sR[2] = b*b + c*c + EPSQ;
    }
    __syncthreads();
    for (int idx = t; idx < 1024; idx += 256){
        int i = idx >> 5, j = idx & 31;
        float q = 0.0f, p = 0.0f;
        for (int k = 0; k < 32; ++k){
            q = fmaf(sL[i*32+k],  sL[j*32+k],  q);
            p = fmaf(sLP[i*32+k], sLP[j*32+k], p);
        }
        if (i == j){ q += EPSQ; p += EPSQ; }
        sQ[idx] = q; sP[idx] = p;
    }
    for (int kp = 1; kp < 4; ++kp){
        __syncthreads();
        if (t < 64){
            int i = t >> 1, c = t & 1;
            float a = 0.0f;
            for (int j = 0; j < 32; ++j) a = fmaf(sA[i*32+j], sPow[kp-1][j*2+c], a);
            sPow[kp][t] = a;
        }
    }
    __syncthreads();
    for (int idx = t; idx < 1280; idx += 256){
        int r = idx / 10, c = idx % 10;
        int bi = r >> 5, ri = r & 31, bj = c >> 1, cj = c & 1;
        sBh[idx] = (bj <= bi) ? sPow[bi-bj][ri*2+cj] : 0.0f;
    }
    __syncthreads();
    for (int idx = t; idx < 1280; idx += 256){
        int r = idx / 10, c = idx % 10;
        int bi = r >> 5, ri = r & 31;
        const float* Qd = (bi < 3) ? sQ : sP;
        float a = 0.0f;
        for (int k = 0; k < 32; ++k) a = fmaf(Qd[ri*32+k], sBh[(bi*32+k)*10+c], a);
        sQB[idx] = a;
    }
    __syncthreads();
    if (t < 120){
        int i = t / 12, j = t % 12;
        float a = 0.0f;
        if (j < 10){
            for (int r = 0; r < 128; ++r) a = fmaf(sBh[r*10+i], sQB[r*10+j], a);
            if ((i >> 1) == (j >> 1)) a += sR[(i&1)+(j&1)];
        }
        ws[QM_OFF + t] = a;
    }
    for (int idx = t; idx < 144*12; idx += 256){
        int m = idx / 12, i = idx % 12;
        float v = 0.0f;
        if (i < 10 && m < MIx) v = (m < 10) ? ((i == m) ? 1.0f : 0.0f) : sBh[(m-10)*10 + i];
        ws[G_OFF + idx] = v;
    }
    for (int m = t; m < 144; m += 256){
        float hv = 0.0f;
        if (m < MIx){
            hv = s0[m];
            if (m < 10) hv += u0[m];
            else { for (int i = 0; i < 10; ++i) hv = fmaf(sBh[(m-10)*10+i], u0[i], hv); }
        }
        ws[H_OFF + m] = hv;
    }
}

// ---------- fc2 with BN1-finalize folded in-block ----------
// w1/w2/b1 inner-loop addresses are wave-uniform: readfirstlane + __restrict__
// lets the backend emit scalar (s_load) instead of vector loads.
__global__ __launch_bounds__(512) void k_fc2(const float* __restrict__ x, const float* __restrict__ w1,
                                             const float* __restrict__ w2, const float* __restrict__ b1v,
                                             const float* __restrict__ b2v, const float* __restrict__ g1,
                                             const float* __restrict__ bb1, float* __restrict__ ws){
    __shared__ float sA1[1024], sC1[1024];
    __shared__ float pacc[512*10];   // 20 KB
    int t = threadIdx.x;
    #pragma unroll
    for (int k = t; k < 1024; k += 512){
        float ssum = 0.0f, qsum = 0.0f;
        #pragma unroll
        for (int b = 0; b < 4; ++b){
            ssum += ws[P1S_OFF + b*1024 + k];
            qsum += ws[P1Q_OFF + b*1024 + k];
        }
        float mu  = ssum * (1.0f/16384.0f);
        float var = qsum * (1.0f/16384.0f) - mu*mu;
        float a1 = g1[k] / sqrtf(var + BNEPS);
        sA1[k] = a1;
        sC1[k] = bb1[k] - mu * a1;
    }
    int r = t & 63;
    int q = t >> 6;                  // 0..7: wave owns k-eighth
    int row = blockIdx.x * 64 + r;
    const float4* xg4 = (const float4*)(x + (size_t)row * 32);
    float4 xr[8];
    #pragma unroll
    for (int i = 0; i < 8; ++i) xr[i] = xg4[i];
    float acc[10];
    #pragma unroll
    for (int j = 0; j < 10; ++j) acc[j] = 0.0f;
    const float4* w1g = (const float4*)w1;
    __syncthreads();
    #pragma unroll 2
    for (int kk = 0; kk < 128; ++kk){
        int kl = __builtin_amdgcn_readfirstlane(q*128 + kk);   // wave-uniform
        float a0 = 0, a1 = 0, a2 = 0, a3 = 0;
        #pragma unroll
        for (int i = 0; i < 8; ++i){
            float4 wv = w1g[kl*8 + i];
            float4 xv = xr[i];
            a0 = fmaf(xv.x, wv.x, a0);
            a1 = fmaf(xv.y, wv.y, a1);
            a2 = fmaf(xv.z, wv.z, a2);
            a3 = fmaf(xv.w, wv.w, a3);
        }
        float h = fmaf(lrelu((a0 + a1) + (a2 + a3) + b1v[kl]), sA1[kl], sC1[kl]);
        #pragma unroll
        for (int j = 0; j < 10; ++j) acc[j] = fmaf(h, w2[j*1024 + kl], acc[j]);
    }
    #pragma unroll
    for (int j = 0; j < 10; ++j) pacc[t*10 + j] = acc[j];
    __syncthreads();
    if (t < 64){
        float pv[10];
        #pragma unroll
        for (int j = 0; j < 10; ++j){
            float a = b2v[j];
            #pragma unroll
            for (int w = 0; w < 8; ++w) a += pacc[(w*64 + t)*10 + j];
            pv[j] = lrelu(a);
        }
        #pragma unroll
        for (int j = 0; j < 10; ++j) ws[PRAW_OFF + (size_t)(blockIdx.x*64 + t)*10 + j] = pv[j];
        float sv[10], qv[10];
        #pragma unroll
        for (int j = 0; j < 10; ++j){ sv[j] = pv[j]; qv[j] = pv[j]*pv[j]; }
        #pragma unroll
        for (int m = 1; m < 64; m <<= 1){
            #pragma unroll
            for (int j = 0; j < 10; ++j){
                sv[j] += __shfl_xor(sv[j], m);
                qv[j] += __shfl_xor(qv[j], m);
            }
        }
        if (t == 0){
            int base = P2_OFF + (blockIdx.x & 15) * 20;
            #pragma unroll
            for (int j = 0; j < 10; ++j){
                atomicAdd(&ws[base + j], sv[j]);
                atomicAdd(&ws[base + 10 + j], qv[j]);
            }
        }
    }
}

// ---------- batched IPM: 8 lanes/element, 8 elements per 64-thread block ----------
// Round-12: all G pairs (incl. B=8) + h pairs in registers; 1/s cached across
// loops A/B/C (-34 v_rcp/iter). In-loop LDS is now only sQt2 init (18 b128),
// sQm Q-pass (30 b128, wave-uniform broadcast) and sPV (3 reads). VGPR budget:
// grid caps occupancy at 2 waves/SIMD, so anything <=256 VGPR is free;
// __launch_bounds__(64,2) pins the allocator there.
#define TIX(i,j) ((i)*((i)+1)/2 + (j))

#define PSTEPA(P, B, GP) { \
    v2f sv = s2[P], lv = lam2[P]; \
    v2f isv; isv.x = frcp(sv.x); isv.y = frcp(sv.y); \
    isv2[P] = isv; \
    v2f wv = lv * isv; \
    v2f r = sv - hh[P]; \
    _Pragma("unroll") \
    for (int _i = 0; _i < (B); ++_i) r = pkfma(splat2(z[_i]), GP[_i], r); \
    rp2[P] = r; \
    sl2 = pkfma(sv, lv, sl2); \
    _Pragma("unroll") \
    for (int _i = 0; _i < (B); ++_i){ \
        v2f wg = wv * GP[_i]; \
        _Pragma("unroll") \
        for (int _j = 0; _j <= _i; ++_j) Hm2[TIX(_i,_j)] = pkfma(wg, GP[_j], Hm2[TIX(_i,_j)]); \
    } }

#define PSTEPB(P, B, GP) { \
    v2f lv = lam2[P]; \
    v2f coef = pkfma(lv, rp2[P], smu2) * isv2[P]; \
    _Pragma("unroll") \
    for (int _i = 0; _i < (B); ++_i) racc2[_i] = pkfma(coef, GP[_i], racc2[_i]); }

#define PSTEPC(P, B, GP) { \
    v2f dotv = splat2(0.0f); \
    _Pragma("unroll") \
    for (int _i = 0; _i < (B); ++_i) dotv = pkfma(splat2(dz[_i]), GP[_i], dotv); \
    v2f sv = s2[P], lv = lam2[P]; \
    v2f isv = isv2[P]; \
    v2f dsv = -(rp2[P] + dotv); \
    v2f rcv = pkfma(sv, lv, nsmu2); \
    v2f dlv = -(pkfma(lv, dsv, rcv) * isv); \
    ds2[P] = dsv; dl2[P] = dlv; \
    v2f ilv; ilv.x = frcp(lv.x); ilv.y = frcp(lv.y); \
    av2 = pkmax(av2, pkmax((-dsv)*isv, (-dlv)*ilv)); }

__global__ __launch_bounds__(64, 2) void k_ipm(const float* __restrict__ ws, const float* __restrict__ g2v,
                                               const float* __restrict__ bb2, float* __restrict__ out){
    __shared__ __align__(16) float sQm[120];
    __shared__ __align__(16) float sQt2[72];    // {Q/8, 0} interleaved, tri rows 0..7
    __shared__ __align__(16) float sPV[8*12];
    __shared__ float sA2[10], sC2[10];
    int t = threadIdx.x;
    for (int i = t; i < 120; i += 64) sQm[i] = ws[QM_OFF + i];
    if (t < 36){
        int i = 0;
        #pragma unroll
        for (int r = 1; r < 8; ++r) if (TIX(r,0) <= t) i = r;
        int j = t - TIX(i,0);
        sQt2[t*2]   = ws[QM_OFF + i*12 + j] * 0.125f;
        sQt2[t*2+1] = 0.0f;
    }
    if (t < 10){   // BN2 finalize (redundant per block — trivial)
        float ssum = 0.0f, qsum = 0.0f;
        #pragma unroll
        for (int b = 0; b < 16; ++b){
            ssum += ws[P2_OFF + b*20 + t];
            qsum += ws[P2_OFF + b*20 + 10 + t];
        }
        float mu  = ssum * (1.0f/16384.0f);
        float var = qsum * (1.0f/16384.0f) - mu*mu;
        float a2 = g2v[t] / sqrtf(var + BNEPS);
        sA2[t] = a2;
        sC2[t] = bb2[t] - mu * a2;
    }
    __syncthreads();

    int lg = t & 7;
    int eidx = t >> 3;
    int elem = blockIdx.x * 8 + eidx;
    const float* GB = ws + G_OFF;
    const float4* sQm4 = (const float4*)sQm;

    for (int i = t; i < 80; i += 64){
        int e = i / 10, c = i - e*10;
        int el = blockIdx.x * 8 + e;
        sPV[e*12 + c] = fmaf(ws[PRAW_OFF + (size_t)el*10 + c], sA2[c], sC2[c]);
    }
    // h pair-packed in registers: pair p covers slots 2p,2p+1
    // row(k) = 10 + (k>>2)*32 + (k&3)*8 + lg
    v2f hh[8];
    #pragma unroll
    for (int p = 0; p < 8; ++p){
        int rowa = 10 + (p >> 1)*32 + (2*(p & 1)    )*8 + lg;
        int rowb = 10 + (p >> 1)*32 + (2*(p & 1) + 1)*8 + lg;
        hh[p] = make2(ws[H_OFF + rowa], ws[H_OFF + rowb]);
    }
    // register-resident G pairs: gp[i] = {G[row_a,i], G[row_b,i]}
    v2f g0[2], g1[2], g2r[4], g3r[4], g4r[6], g5r[6], g6r[8], g7r[8];
    {
        int ra, rb;
        ra = 10 + lg; rb = 18 + lg;
        #pragma unroll
        for (int i = 0; i < 2; ++i) g0[i] = make2(GB[ra*12+i], GB[rb*12+i]);
        ra = 26 + lg; rb = 34 + lg;
        #pragma unroll
        for (int i = 0; i < 2; ++i) g1[i] = make2(GB[ra*12+i], GB[rb*12+i]);
        ra = 42 + lg; rb = 50 + lg;
        #pragma unroll
        for (int i = 0; i < 4; ++i) g2r[i] = make2(GB[ra*12+i], GB[rb*12+i]);
        ra = 58 + lg; rb = 66 + lg;
        #pragma unroll
        for (int i = 0; i < 4; ++i) g3r[i] = make2(GB[ra*12+i], GB[rb*12+i]);
        ra = 74 + lg; rb = 82 + lg;
        #pragma unroll
        for (int i = 0; i < 6; ++i) g4r[i] = make2(GB[ra*12+i], GB[rb*12+i]);
        ra = 90 + lg; rb = 98 + lg;
        #pragma unroll
        for (int i = 0; i < 6; ++i) g5r[i] = make2(GB[ra*12+i], GB[rb*12+i]);
        ra = 106 + lg; rb = 114 + lg;
        #pragma unroll
        for (int i = 0; i < 8; ++i) g6r[i] = make2(GB[ra*12+i], GB[rb*12+i]);
        ra = 122 + lg; rb = 130 + lg;
        #pragma unroll
        for (int i = 0; i < 8; ++i) g7r[i] = make2(GB[ra*12+i], GB[rb*12+i]);
    }
    float h16 = ws[H_OFF + lg];                          // identity rows 0..7
    float h17 = (lg < 2) ? ws[H_OFF + 8 + lg] : 1.0f;    // identity rows 8,9
    __syncthreads();

    float pv[10];
    {
        const float4* pv4 = (const float4*)(sPV + eidx*12);
        float4 pa = pv4[0], pb = pv4[1];
        const float2* pv2 = (const float2*)(sPV + eidx*12 + 8);
        float2 pc = pv2[0];
        pv[0]=pa.x; pv[1]=pa.y; pv[2]=pa.z; pv[3]=pa.w;
        pv[4]=pb.x; pv[5]=pb.y; pv[6]=pb.z; pv[7]=pb.w;
        pv[8]=pc.x; pv[9]=pc.y;
    }

    float z[10];
    #pragma unroll
    for (int i = 0; i < 10; ++i) z[i] = 0.0f;
    v2f s2[8], lam2[8];
    #pragma unroll
    for (int p = 0; p < 8; ++p){ s2[p] = splat2(1.0f); lam2[p] = splat2(1.0f); }
    float s16v = 1.0f, s17v = 1.0f, lam16v = 1.0f;
    float lam17v = (lg < 2) ? 1.0f : 0.0f;

    #pragma unroll 1
    for (int it = 0; it < ITERS; ++it){
        float is16 = frcp(s16v), is17 = frcp(s17v);
        v2f isv2[8];
        v2f Hm2[36];
        {
            const v2f* qt2 = (const v2f*)sQt2;
            #pragma unroll
            for (int i = 0; i < 36; ++i) Hm2[i] = qt2[i];   // {Q/8, 0}
        }
        v2f sl2 = splat2(0.0f);
        v2f rp2[8];
        float rp16, rp17;
        // ---- loop A: rp + Hm (paired)
        PSTEPA(0, 2, g0)  PSTEPA(1, 2, g1)
        PSTEPA(2, 4, g2r) PSTEPA(3, 4, g3r)
        PSTEPA(4, 6, g4r) PSTEPA(5, 6, g5r)
        PSTEPA(6, 8, g6r) PSTEPA(7, 8, g7r)
        // ---- identity slots 16 (rows 0..7) and 17 (rows 8,9 on lanes 0,1)
        float w16, w17, sl_s;
        {
            float zs = z[0];
            #pragma unroll
            for (int i = 1; i < 8; ++i) zs = (lg == i) ? z[i] : zs;
            rp16 = zs + s16v - h16;
            sl_s = s16v * lam16v;
            w16 = lam16v * is16;
            float zs17 = (lg == 1) ? z[9] : z[8];
            rp17 = zs17 + s17v - h17;
            sl_s = fmaf(s17v, lam17v, sl_s);
            w17 = lam17v * is17;
        }
        // ---- fold pairs -> scalar, add identity diag, DPP 8-lane all-reduce
        float Hm[55];
        #pragma unroll
        for (int i = 0; i < 36; ++i) Hm[i] = Hm2[i].x + Hm2[i].y;
        #pragma unroll
        for (int i = 0; i < 8; ++i) Hm[TIX(i,i)] += (lg == i) ? w16 : 0.0f;
        float d88 = (lg == 0) ? w17 : 0.0f;
        float d99 = (lg == 1) ? w17 : 0.0f;
        float sl = sl2.x + sl2.y + sl_s;
        #pragma unroll
        for (int i = 0; i < 36; ++i) Hm[i] = red8_add(Hm[i]);
        d88 = red8_add(d88);
        d99 = red8_add(d99);
        sl = red8_add(sl);
        float smu = SIGMA_C * sl * (1.0f/138.0f);
        __asm__ __volatile__("" ::: "memory");   // keep sQm reads in-loop
        // ---- loop B: racc = sum_k g_k*(lam_k*rp_k+smu)/s_k (paired, .x=even .y=odd)
        v2f smu2 = splat2(smu);
        v2f racc2[8];
        #pragma unroll
        for (int i = 0; i < 8; ++i) racc2[i] = splat2(0.0f);
        PSTEPB(0, 2, g0)  PSTEPB(1, 2, g1)
        PSTEPB(2, 4, g2r) PSTEPB(3, 4, g3r)
        PSTEPB(4, 6, g4r) PSTEPB(5, 6, g5r)
        PSTEPB(6, 8, g6r) PSTEPB(7, 8, g7r)
        float coef16 = is16 * fmaf(lam16v, rp16, smu);
        float coef17 = is17 * fmaf(lam17v, rp17, smu);
        coef17 = (lg < 2) ? coef17 : 0.0f;
        float rs[10];
        #pragma unroll
        for (int i = 0; i < 8; ++i){
            float v = racc2[i].x + racc2[i].y;
            v += (lg == i) ? coef16 : 0.0f;
            rs[i] = red8_add(v);
        }
        rs[8] = red8_add((lg == 0) ? coef17 : 0.0f);
        rs[9] = red8_add((lg == 1) ? coef17 : 0.0f);
        // ---- rhs = -(p + racc) - Q z (packed Q-pass); rows 8,9 of H assigned
        v2f rhs2[5];
        rhs2[0] = make2(-(pv[0] + rs[0]), -(pv[1] + rs[1]));
        rhs2[1] = make2(-(pv[2] + rs[2]), -(pv[3] + rs[3]));
        rhs2[2] = make2(-(pv[4] + rs[4]), -(pv[5] + rs[5]));
        rhs2[3] = make2(-(pv[6] + rs[6]), -(pv[7] + rs[7]));
        rhs2[4] = make2(-(pv[8] + rs[8]), -(pv[9] + rs[9]));
        #pragma unroll
        for (int j = 0; j < 10; ++j){
            float4 qa = sQm4[j*3+0], qb = sQm4[j*3+1], qc = sQm4[j*3+2];
            v2f mz = splat2(-z[j]);
            rhs2[0] = pkfma(mz, make2(qa.x, qa.y), rhs2[0]);
            rhs2[1] = pkfma(mz, make2(qa.z, qa.w), rhs2[1]);
            rhs2[2] = pkfma(mz, make2(qb.x, qb.y), rhs2[2]);
            rhs2[3] = pkfma(mz, make2(qb.z, qb.w), rhs2[3]);
            rhs2[4] = pkfma(mz, make2(qc.x, qc.y), rhs2[4]);
            if (j >= 8){
                float q[10] = {qa.x,qa.y,qa.z,qa.w, qb.x,qb.y,qb.z,qb.w, qc.x,qc.y};
                #pragma unroll
                for (int i = 0; i <= j; ++i) Hm[TIX(j,i)] = q[i];
            }
        }
        Hm[TIX(8,8)] += d88;
        Hm[TIX(9,9)] += d99;
        float rhs[10] = {rhs2[0].x, rhs2[0].y, rhs2[1].x, rhs2[1].y, rhs2[2].x,
                         rhs2[2].y, rhs2[3].x, rhs2[3].y, rhs2[4].x, rhs2[4].y};
        // ---- Cholesky (reciprocal diag in place)
        #pragma unroll
        for (int j = 0; j < 10; ++j){
            float d = Hm[TIX(j,j)];
            #pragma unroll
            for (int k2 = 0; k2 < j; ++k2){ float v = Hm[TIX(j,k2)]; d = fmaf(-v, v, d); }
            d = fmaxf(d, 1e-30f);
            float rinv = frsq(d);
            Hm[TIX(j,j)] = rinv;
            #pragma unroll
            for (int i = j+1; i < 10; ++i){
                float v2 = Hm[TIX(i,j)];
                #pragma unroll
                for (int k2 = 0; k2 < j; ++k2) v2 = fmaf(-Hm[TIX(i,k2)], Hm[TIX(j,k2)], v2);
                Hm[TIX(i,j)] = v2 * rinv;
            }
        }
        #pragma unroll
        for (int i = 0; i < 10; ++i){
            float v2 = rhs[i];
            #pragma unroll
            for (int k2 = 0; k2 < i; ++k2) v2 = fmaf(-Hm[TIX(i,k2)], rhs[k2], v2);
            rhs[i] = v2 * Hm[TIX(i,i)];
        }
        float dz[10];
        #pragma unroll
        for (int i = 9; i >= 0; --i){
            float v2 = rhs[i];
            #pragma unroll
            for (int k2 = i+1; k2 < 10; ++k2) v2 = fmaf(-Hm[TIX(k2,i)], dz[k2], v2);
            dz[i] = v2 * Hm[TIX(i,i)];
        }
        __asm__ __volatile__("" ::: "memory");
        // ---- loop C: steps + alpha (paired; max-of-inverse-ratios)
        v2f nsmu2 = splat2(-smu);
        v2f ds2[8], dl2[8];
        v2f av2 = splat2(0.0f);
        PSTEPC(0, 2, g0)  PSTEPC(1, 2, g1)
        PSTEPC(2, 4, g2r) PSTEPC(3, 4, g3r)
        PSTEPC(4, 6, g4r) PSTEPC(5, 6, g5r)
        PSTEPC(6, 8, g6r) PSTEPC(7, 8, g7r)
        float ds16, dl16, ds17, dl17;
        float ainv = fmaxf(av2.x, av2.y);
        {
            float dzs = dz[0];
            #pragma unroll
            for (int i = 1; i < 8; ++i) dzs = (lg == i) ? dz[i] : dzs;
            float dsk = -rp16 - dzs;
            float rc = fmaf(s16v, lam16v, -smu);
            float dlk = -(rc + lam16v * dsk) * is16;
            ds16 = dsk; dl16 = dlk;
            ainv = fmaxf(ainv, fmaxf(-dsk * is16, -dlk * frcp(lam16v)));
        }
        {
            float dzs = (lg == 1) ? dz[9] : dz[8];
            bool val = lg < 2;
            float dsk = val ? (-rp17 - dzs) : 0.0f;
            float rc = fmaf(s17v, lam17v, -smu);
            float dlk = -(rc + lam17v * dsk) * is17;
            dlk = val ? dlk : 0.0f;
            ds17 = dsk; dl17 = dlk;
            float cand = fmaxf(-dsk * is17, -dlk * frcp(lam17v));
            ainv = fmaxf(ainv, val ? cand : 0.0f);
        }
        ainv = red8_max(ainv);
        float alpha = fminf(1.0f, 0.99f * frcp(fmaxf(ainv, 1e-30f)));
        // ---- updates (packed s/lam)
        v2f al2 = splat2(alpha);
        #pragma unroll
        for (int i = 0; i < 10; ++i) z[i] = fmaf(alpha, dz[i], z[i]);
        #pragma unroll
        for (int p = 0; p < 8; ++p){
            s2[p]   = pkfma(al2, ds2[p], s2[p]);
            lam2[p] = pkfma(al2, dl2[p], lam2[p]);
        }
        s16v   = fmaf(alpha, ds16, s16v);
        s17v   = fmaf(alpha, ds17, s17v);
        lam16v = fmaf(alpha, dl16, lam16v);
        lam17v = fmaf(alpha, dl17, lam17v);
    }
    if (lg == 0) out[elem] = z[0];
}

extern "C" void kernel_launch(void* const* d_in, const int* in_sizes, int n_in,
                              void* d_out, int out_size, void* d_ws, size_t ws_size,
                              hipStream_t stream){
    const float* x   = (const float*)d_in[0];
    const float* w1  = (const float*)d_in[1];
    const float* b1  = (const float*)d_in[2];
    const float* w2  = (const float*)d_in[3];
    const float* b2  = (const float*)d_in[4];
    const float* g1  = (const float*)d_in[5];
    const float* bb1 = (const float*)d_in[6];
    const float* g2  = (const float*)d_in[7];
    const float* bb2 = (const float*)d_in[8];
    const float* L   = (const float*)d_in[9];
    const float* LP  = (const float*)d_in[10];
    const float* LR  = (const float*)d_in[11];
    const float* A   = (const float*)d_in[12];
    const float* Bm  = (const float*)d_in[13];
    const float* u0  = (const float*)d_in[14];
    const float* s0  = (const float*)d_in[15];
    float* ws  = (float*)d_ws;
    float* out = (float*)d_out;

    // zero P2 + P1 partial accumulators (floats 2048..10560)
    hipMemsetAsync(ws + P2_OFF, 0, (P1Q_OFF + 4096 - P2_OFF) * sizeof(float), stream);
    hipLaunchKernelGGL(k_buildstats, dim3(513), dim3(256), 0, stream,
                       L, LP, LR, A, Bm, u0, s0, x, w1, b1, ws);
    hipLaunchKernelGGL(k_fc2, dim3(256), dim3(512), 0, stream, x, w1, w2, b1, b2, g1, bb1, ws);
    hipLaunchKernelGGL(k_ipm, dim3(2048), dim3(64), 0, stream, ws, g2, bb2, out);
}

// Round 3
// 359.125 us; speedup vs baseline: 1.1248x; 1.1248x over previous
//
#include <hip/hip_runtime.h>
#include <math.h>

#define NIx 32
#define NOx 2
#define NUx 10
#define NHx 1024
#define NBx 16384
#define MIx 138
#define EPSQ 1e-4f
#define BNEPS 1e-5f
#define ITERS 30
#define SLOPE 0.2f
#define SIGMA_C 0.1f

// workspace layout (float offsets). Max = 174400 floats = 697.6 KB (< proven 723 KB).
#define QM_OFF 0        // 120 (pad 128)
#define G_OFF 128       // 144 x 12 -> 1856
#define H_OFF 1856      // 144 (pad 2048)
#define P2_OFF 2048     // 16 bufs x 20 (sum[10],sq[10]) = 320 (pad 2368)
#define P1S_OFF 2368    // 4 bufs x 1024 col-sums
#define P1Q_OFF 6464    // 4 bufs x 1024 col-sumsq -> 10560
#define PRAW_OFF 10560  // 16384 x 10 -> 174400
// memset zeroes [P2_OFF, P1Q_OFF+4096) = floats 2048..10560

__device__ __forceinline__ float frcp(float x){ return __builtin_amdgcn_rcpf(x); }
__device__ __forceinline__ float frsq(float x){ return __builtin_amdgcn_rsqf(x); }
__device__ __forceinline__ float lrelu(float x){ return x > 0.0f ? x : SLOPE * x; }

// packed fp32 helpers. NOTE (round-1 measurement): v_pk_*_f32 is issue-NEUTRAL on
// gfx950. Kept because the pairing structure organizes the code.
typedef float v2f __attribute__((ext_vector_type(2)));
__device__ __forceinline__ v2f make2(float a, float b){ v2f r; r.x = a; r.y = b; return r; }
__device__ __forceinline__ v2f splat2(float a){ v2f r; r.x = a; r.y = a; return r; }
__device__ __forceinline__ v2f pkfma(v2f a, v2f b, v2f c){ return __builtin_elementwise_fma(a, b, c); }
__device__ __forceinline__ v2f pkmax(v2f a, v2f b){ return __builtin_elementwise_max(a, b); }

// ---- DPP cross-lane reductions (VALU, no LDS pipe) ----
template<int CTRL>
__device__ __forceinline__ float dpp_mov(float x){
    int y = __builtin_amdgcn_update_dpp(0, __float_as_int(x), CTRL, 0xF, 0xF, true);
    return __int_as_float(y);
}
// 8-lane all-reduce: xor1 (quad_perm[1,0,3,2]), xor2 (quad_perm[2,3,0,1]),
// then row_half_mirror (0x141: i -> 7-i within each 8 = xor-7) closes the group.
__device__ __forceinline__ float red8_add(float x){
    x += dpp_mov<0xB1>(x);
    x += dpp_mov<0x4E>(x);
    x += dpp_mov<0x141>(x);
    return x;
}
__device__ __forceinline__ float red8_max(float x){
    x = fmaxf(x, dpp_mov<0xB1>(x));
    x = fmaxf(x, dpp_mov<0x4E>(x));
    x = fmaxf(x, dpp_mov<0x141>(x));
    return x;
}

// ---------- merged: blocks 0..511 BN1-stats, block 512 QP-build (independent work) ----------
__global__ __launch_bounds__(256) void k_buildstats(const float* L, const float* LP, const float* LR,
                                                    const float* A, const float* Bm,
                                                    const float* u0, const float* s0,
                                                    const float* x, const float* w1, const float* b1,
                                                    float* ws){
    __shared__ float sL[1024], sLP[1024], sA[1024], sQ[1024], sP[1024];
    __shared__ float sPow[4][64];
    __shared__ float sBh[128*10];
    __shared__ float sQB[128*10];
    __shared__ float sR[3];
    int t = threadIdx.x;
    if (blockIdx.x < 512){
        // ---- BN1 stats path: partial col sum/sumsq into 4 spread buffers ----
        int rb = blockIdx.x >> 2;        // 128 row-groups of 128 rows
        int cb = blockIdx.x & 3;         // 4 col-groups of 256 cols
        int c = cb * 256 + t;
        const float4* wg4 = (const float4*)(w1 + (size_t)c * 32);
        float4 wr[8];
        #pragma unroll
        for (int q = 0; q < 8; ++q) wr[q] = wg4[q];
        float bc = b1[c];
        int r0 = rb * 128;
        float sum = 0.0f, sq = 0.0f;
        #pragma unroll 2
        for (int r = 0; r < 128; ++r){
            // x-row address is wave-uniform: force SGPR base -> s_load (scalar pipe)
            int ro = __builtin_amdgcn_readfirstlane((r0 + r) * 32);
            const float4* xr4 = (const float4*)(x + ro);
            float a0 = 0, a1 = 0, a2 = 0, a3 = 0;
            #pragma unroll
            for (int q = 0; q < 8; ++q){
                float4 v = xr4[q];
                a0 = fmaf(v.x, wr[q].x, a0);
                a1 = fmaf(v.y, wr[q].y, a1);
                a2 = fmaf(v.z, wr[q].z, a2);
                a3 = fmaf(v.w, wr[q].w, a3);
            }
            float h = lrelu((a0 + a1) + (a2 + a3) + bc);
            sum += h; sq = fmaf(h, h, sq);
        }
        int buf = (rb & 3) * 1024 + c;
        atomicAdd(&ws[P1S_OFF + buf], sum);
        atomicAdd(&ws[P1Q_OFF + buf], sq);
        return;
    }
    // ---- QP build path (single block) ----
    for (int idx = t; idx < 1024; idx += 256){
        int i = idx >> 5, j = idx & 31;
        sL[idx]  = (j <= i) ? L[idx]  : 0.0f;
        sLP[idx] = (j <= i) ? LP[idx] : 0.0f;
        sA[idx]  = A[idx];
    }
    if (t < 64) sPow[0][t] = Bm[t];
    if (t == 0){
        float a = LR[0], b = LR[2], c = LR[3];   // tril: [[a,0],[b,c]]
        sR[0] = a*a + EPSQ; sR[1] = a*b; sR[2] = b*b + c*c + EPSQ;
    }
    __syncthreads();
    for (int idx = t; idx < 1024; idx += 256){
        int i = idx >> 5, j = idx & 31;
        float q = 0.0f, p = 0.0f;
        for (int k = 0; k < 32; ++k){
            q = fmaf(sL[i*32+k],  sL[j*32+k],  q);
            p = fmaf(sLP[i*32+k], sLP[j*32+k], p);
        }
        if (i == j){ q += EPSQ; p += EPSQ; }
        sQ[idx] = q; sP[idx] = p;
    }
    for (int kp = 1; kp < 4; ++kp){
        __syncthreads();
        if (t < 64){
            int i = t >> 1, c = t & 1;
            float a = 0.0f;
            for (int j = 0; j < 32; ++j) a = fmaf(sA[i*32+j], sPow[kp-1][j*2+c], a);
            sPow[kp][t] = a;
        }
    }
    __syncthreads();
    for (int idx = t; idx < 1280; idx += 256){
        int r = idx / 10, c = idx % 10;
        int bi = r >> 5, ri = r & 31, bj = c >> 1, cj = c & 1;
        sBh[idx] = (bj <= bi) ? sPow[bi-bj][ri*2+cj] : 0.0f;
    }
    __syncthreads();
    for (int idx = t; idx < 1280; idx += 256){
        int r = idx / 10, c = idx % 10;
        int bi = r >> 5, ri = r & 31;
        const float* Qd = (bi < 3) ? sQ : sP;
        float a = 0.0f;
        for (int k = 0; k < 32; ++k) a = fmaf(Qd[ri*32+k], sBh[(bi*32+k)*10+c], a);
        sQB[idx] = a;
    }
    __syncthreads();
    if (t < 120){
        int i = t / 12, j = t % 12;
        float a = 0.0f;
        if (j < 10){
            for (int r = 0; r < 128; ++r) a = fmaf(sBh[r*10+i], sQB[r*10+j], a);
            if ((i >> 1) == (j >> 1)) a += sR[(i&1)+(j&1)];
        }
        ws[QM_OFF + t] = a;
    }
    for (int idx = t; idx < 144*12; idx += 256){
        int m = idx / 12, i = idx % 12;
        float v = 0.0f;
        if (i < 10 && m < MIx) v = (m < 10) ? ((i == m) ? 1.0f : 0.0f) : sBh[(m-10)*10 + i];
        ws[G_OFF + idx] = v;
    }
    for (int m = t; m < 144; m += 256){
        float hv = 0.0f;
        if (m < MIx){
            hv = s0[m];
            if (m < 10) hv += u0[m];
            else { for (int i = 0; i < 10; ++i) hv = fmaf(sBh[(m-10)*10+i], u0[i], hv); }
        }
        ws[H_OFF + m] = hv;
    }
}

// ---------- fc2 with BN1-finalize folded in-block ----------
// Round-13: kill the w2/b1 scalar-load storm. Inner loop previously issued
// 10 s_loads of w2[j*1024+kl] (4 B each, lines 4 KB apart -> sL1-hostile) + 1
// of b1v[kl] per kk. Now w2 is staged TRANSPOSED in LDS (sW2t[kl*12+j], 48 KB)
// + b1 (4 KB), read as 4 wave-uniform broadcast ds_reads per kk. The w2t/b1
// region is aliased with pacc (used only after the kk-loop, barrier-separated):
// total LDS = 8 KB (sA1/sC1) + 53.25 KB = 61.25 KB <= 64 KB.
#define FC2_B1_OFF 12288   // floats into sBuf
__global__ __launch_bounds__(512) void k_fc2(const float* __restrict__ x, const float* __restrict__ w1,
                                             const float* __restrict__ w2, const float* __restrict__ b1v,
                                             const float* __restrict__ b2v, const float* __restrict__ g1,
                                             const float* __restrict__ bb1, float* __restrict__ ws){
    __shared__ float sA1[1024], sC1[1024];
    __shared__ __align__(16) float sBuf[13312];  // [0..12287]=w2t (kl*12+j), [12288..13311]=b1; pacc aliases [0..5119]
    int t = threadIdx.x;
    // stage w2 transposed + b1 (coalesced global reads; one-time 8-way LDS write conflict is fine)
    for (int idx = t; idx < 10240; idx += 512){
        int j = idx >> 10, kl = idx & 1023;
        sBuf[kl*12 + j] = w2[idx];
    }
    for (int k = t; k < 1024; k += 512) sBuf[FC2_B1_OFF + k] = b1v[k];
    #pragma unroll
    for (int k = t; k < 1024; k += 512){
        float ssum = 0.0f, qsum = 0.0f;
        #pragma unroll
        for (int b = 0; b < 4; ++b){
            ssum += ws[P1S_OFF + b*1024 + k];
            qsum += ws[P1Q_OFF + b*1024 + k];
        }
        float mu  = ssum * (1.0f/16384.0f);
        float var = qsum * (1.0f/16384.0f) - mu*mu;
        float a1 = g1[k] / sqrtf(var + BNEPS);
        sA1[k] = a1;
        sC1[k] = bb1[k] - mu * a1;
    }
    int r = t & 63;
    int q = t >> 6;                  // 0..7: wave owns k-eighth
    int row = blockIdx.x * 64 + r;
    const float4* xg4 = (const float4*)(x + (size_t)row * 32);
    float4 xr[8];
    #pragma unroll
    for (int i = 0; i < 8; ++i) xr[i] = xg4[i];
    float acc[10];
    #pragma unroll
    for (int j = 0; j < 10; ++j) acc[j] = 0.0f;
    const float4* w1g = (const float4*)w1;
    __syncthreads();
    #pragma unroll 2
    for (int kk = 0; kk < 128; ++kk){
        int kl = __builtin_amdgcn_readfirstlane(q*128 + kk);   // wave-uniform
        float a0 = 0, a1 = 0, a2 = 0, a3 = 0;
        #pragma unroll
        for (int i = 0; i < 8; ++i){
            float4 wv = w1g[kl*8 + i];
            float4 xv = xr[i];
            a0 = fmaf(xv.x, wv.x, a0);
            a1 = fmaf(xv.y, wv.y, a1);
            a2 = fmaf(xv.z, wv.z, a2);
            a3 = fmaf(xv.w, wv.w, a3);
        }
        float h = fmaf(lrelu((a0 + a1) + (a2 + a3) + sBuf[FC2_B1_OFF + kl]), sA1[kl], sC1[kl]);
        const float4* wt4 = (const float4*)(sBuf + kl*12);
        float4 wa = wt4[0], wb = wt4[1];
        float2 wc = *(const float2*)(sBuf + kl*12 + 8);
        acc[0] = fmaf(h, wa.x, acc[0]); acc[1] = fmaf(h, wa.y, acc[1]);
        acc[2] = fmaf(h, wa.z, acc[2]); acc[3] = fmaf(h, wa.w, acc[3]);
        acc[4] = fmaf(h, wb.x, acc[4]); acc[5] = fmaf(h, wb.y, acc[5]);
        acc[6] = fmaf(h, wb.z, acc[6]); acc[7] = fmaf(h, wb.w, acc[7]);
        acc[8] = fmaf(h, wc.x, acc[8]); acc[9] = fmaf(h, wc.y, acc[9]);
    }
    __syncthreads();   // all waves done reading w2t/b1 before pacc aliases the region
    float* pacc = sBuf;
    #pragma unroll
    for (int j = 0; j < 10; ++j) pacc[t*10 + j] = acc[j];
    __syncthreads();
    if (t < 64){
        float pv[10];
        #pragma unroll
        for (int j = 0; j < 10; ++j){
            float a = b2v[j];
            #pragma unroll
            for (int w = 0; w < 8; ++w) a += pacc[(w*64 + t)*10 + j];
            pv[j] = lrelu(a);
        }
        #pragma unroll
        for (int j = 0; j < 10; ++j) ws[PRAW_OFF + (size_t)(blockIdx.x*64 + t)*10 + j] = pv[j];
        float sv[10], qv[10];
        #pragma unroll
        for (int j = 0; j < 10; ++j){ sv[j] = pv[j]; qv[j] = pv[j]*pv[j]; }
        #pragma unroll
        for (int m = 1; m < 64; m <<= 1){
            #pragma unroll
            for (int j = 0; j < 10; ++j){
                sv[j] += __shfl_xor(sv[j], m);
                qv[j] += __shfl_xor(qv[j], m);
            }
        }
        if (t == 0){
            int base = P2_OFF + (blockIdx.x & 15) * 20;
            #pragma unroll
            for (int j = 0; j < 10; ++j){
                atomicAdd(&ws[base + j], sv[j]);
                atomicAdd(&ws[base + 10 + j], qv[j]);
            }
        }
    }
}

// ---------- batched IPM: 8 lanes/element, 8 elements per 64-thread block ----------
// Round-11 structure (REVERTED round-12's register promotion: allocator hard-caps
// this kernel at 128 VGPR — promoting g6/g7/hh/isv spilled to scratch, 137 MB
// of WRITE_SIZE, +41 us. 128-VGPR envelope is the law here.)
//   16 B_hat slots paired into v2f; G pairs B=2/4/6 in registers; B=8 pairs in
//   LDS (pair-packed, stride 36); h pairs in LDS; rp in registers.
#define TIX(i,j) ((i)*((i)+1)/2 + (j))

#define PSTEPA(P, B, GP) { \
    v2f sv = s2[P], lv = lam2[P]; \
    v2f isv; isv.x = frcp(sv.x); isv.y = frcp(sv.y); \
    v2f wv = lv * isv; \
    v2f r = sv - *(const v2f*)(sHH2 + (P)*16 + lg*2); \
    _Pragma("unroll") \
    for (int _i = 0; _i < (B); ++_i) r = pkfma(splat2(z[_i]), GP[_i], r); \
    rp2[P] = r; \
    sl2 = pkfma(sv, lv, sl2); \
    _Pragma("unroll") \
    for (int _i = 0; _i < (B); ++_i){ \
        v2f wg = wv * GP[_i]; \
        _Pragma("unroll") \
        for (int _j = 0; _j <= _i; ++_j) Hm2[TIX(_i,_j)] = pkfma(wg, GP[_j], Hm2[TIX(_i,_j)]); \
    } }

#define PSTEPB(P, B, GP) { \
    v2f sv = s2[P], lv = lam2[P]; \
    v2f isv; isv.x = frcp(sv.x); isv.y = frcp(sv.y); \
    v2f coef = pkfma(lv, rp2[P], smu2) * isv; \
    _Pragma("unroll") \
    for (int _i = 0; _i < (B); ++_i) racc2[_i] = pkfma(coef, GP[_i], racc2[_i]); }

#define PSTEPC(P, B, GP) { \
    v2f dotv = splat2(0.0f); \
    _Pragma("unroll") \
    for (int _i = 0; _i < (B); ++_i) dotv = pkfma(splat2(dz[_i]), GP[_i], dotv); \
    v2f sv = s2[P], lv = lam2[P]; \
    v2f isv; isv.x = frcp(sv.x); isv.y = frcp(sv.y); \
    v2f dsv = -(rp2[P] + dotv); \
    v2f rcv = pkfma(sv, lv, nsmu2); \
    v2f dlv = -(pkfma(lv, dsv, rcv) * isv); \
    ds2[P] = dsv; dl2[P] = dlv; \
    v2f ilv; ilv.x = frcp(lv.x); ilv.y = frcp(lv.y); \
    av2 = pkmax(av2, pkmax((-dsv)*isv, (-dlv)*ilv)); }

#define LOADP(GP, PP) v2f GP[8]; { \
    const float4* _g4 = (const float4*)(sG3 + lg*36 + (PP)*16); \
    float4 _a = _g4[0], _b = _g4[1], _c = _g4[2], _d = _g4[3]; \
    GP[0] = make2(_a.x,_a.y); GP[1] = make2(_a.z,_a.w); \
    GP[2] = make2(_b.x,_b.y); GP[3] = make2(_b.z,_b.w); \
    GP[4] = make2(_c.x,_c.y); GP[5] = make2(_c.z,_c.w); \
    GP[6] = make2(_d.x,_d.y); GP[7] = make2(_d.z,_d.w); }

__global__ __launch_bounds__(64, 2) void k_ipm(const float* __restrict__ ws, const float* __restrict__ g2v,
                                               const float* __restrict__ bb2, float* __restrict__ out){
    __shared__ __align__(16) float sQm[120];
    __shared__ __align__(16) float sQt2[72];    // {Q/8, 0} interleaved, tri rows 0..7
    __shared__ __align__(16) float sPV[8*12];
    __shared__ __align__(16) float sG3[8*36];   // B=8 G pairs, pair-packed per lg
    __shared__ __align__(16) float sHH2[128];   // h pair-packed: [p*16 + lg*2 + c]
    __shared__ float sA2[10], sC2[10];
    int t = threadIdx.x;
    for (int i = t; i < 120; i += 64) sQm[i] = ws[QM_OFF + i];
    if (t < 36){
        int i = 0;
        #pragma unroll
        for (int r = 1; r < 8; ++r) if (TIX(r,0) <= t) i = r;
        int j = t - TIX(i,0);
        sQt2[t*2]   = ws[QM_OFF + i*12 + j] * 0.125f;
        sQt2[t*2+1] = 0.0f;
    }
    if (t < 10){   // BN2 finalize (redundant per block — trivial)
        float ssum = 0.0f, qsum = 0.0f;
        #pragma unroll
        for (int b = 0; b < 16; ++b){
            ssum += ws[P2_OFF + b*20 + t];
            qsum += ws[P2_OFF + b*20 + 10 + t];
        }
        float mu  = ssum * (1.0f/16384.0f);
        float var = qsum * (1.0f/16384.0f) - mu*mu;
        float a2 = g2v[t] / sqrtf(var + BNEPS);
        sA2[t] = a2;
        sC2[t] = bb2[t] - mu * a2;
    }
    __syncthreads();

    int lg = t & 7;
    int eidx = t >> 3;
    int elem = blockIdx.x * 8 + eidx;
    const float* GB = ws + G_OFF;
    const float4* sQm4 = (const float4*)sQm;

    for (int i = t; i < 80; i += 64){
        int e = i / 10, c = i - e*10;
        int el = blockIdx.x * 8 + e;
        sPV[e*12 + c] = fmaf(ws[PRAW_OFF + (size_t)el*10 + c], sA2[c], sC2[c]);
    }
    // h pair-packed: pair p covers slots 2p,2p+1 (block b=p>>1, k&3 = 2(p&1)+c)
    for (int i = t; i < 128; i += 64){
        int c = i & 1, lgx = (i >> 1) & 7, p = i >> 4;
        int row = 10 + (p >> 1)*32 + (2*(p & 1) + c)*8 + lgx;
        sHH2[p*16 + lgx*2 + c] = ws[H_OFF + row];
    }
    // B=8 pairs (slots 12..15) pair-packed in LDS: sG3[lg*36 + pp*16 + i*2 + c]
    for (int i = t; i < 256; i += 64){
        int c = i & 1, ii = (i >> 1) & 7, pp = (i >> 4) & 1, lgx = i >> 5;
        int row = 106 + (pp*2 + c)*8 + lgx;
        sG3[lgx*36 + pp*16 + ii*2 + c] = GB[row*12 + ii];
    }
    // register-resident G pairs (B=2,4,6): gp[i] = {G[row_a,i], G[row_b,i]}
    v2f g0[2], g1[2], g2r[4], g3r[4], g4r[6], g5r[6];
    {
        int ra, rb;
        ra = 10 + lg; rb = 18 + lg;
        #pragma unroll
        for (int i = 0; i < 2; ++i) g0[i] = make2(GB[ra*12+i], GB[rb*12+i]);
        ra = 26 + lg; rb = 34 + lg;
        #pragma unroll
        for (int i = 0; i < 2; ++i) g1[i] = make2(GB[ra*12+i], GB[rb*12+i]);
        ra = 42 + lg; rb = 50 + lg;
        #pragma unroll
        for (int i = 0; i < 4; ++i) g2r[i] = make2(GB[ra*12+i], GB[rb*12+i]);
        ra = 58 + lg; rb = 66 + lg;
        #pragma unroll
        for (int i = 0; i < 4; ++i) g3r[i] = make2(GB[ra*12+i], GB[rb*12+i]);
        ra = 74 + lg; rb = 82 + lg;
        #pragma unroll
        for (int i = 0; i < 6; ++i) g4r[i] = make2(GB[ra*12+i], GB[rb*12+i]);
        ra = 90 + lg; rb = 98 + lg;
        #pragma unroll
        for (int i = 0; i < 6; ++i) g5r[i] = make2(GB[ra*12+i], GB[rb*12+i]);
    }
    float h16 = ws[H_OFF + lg];                          // identity rows 0..7
    float h17 = (lg < 2) ? ws[H_OFF + 8 + lg] : 1.0f;    // identity rows 8,9
    __syncthreads();

    float z[10];
    #pragma unroll
    for (int i = 0; i < 10; ++i) z[i] = 0.0f;
    v2f s2[8], lam2[8];
    #pragma unroll
    for (int p = 0; p < 8; ++p){ s2[p] = splat2(1.0f); lam2[p] = splat2(1.0f); }
    float s16v = 1.0f, s17v = 1.0f, lam16v = 1.0f;
    float lam17v = (lg < 2) ? 1.0f : 0.0f;

    #pragma unroll 1
    for (int it = 0; it < ITERS; ++it){
        v2f Hm2[36];
        {
            const v2f* qt2 = (const v2f*)sQt2;
            #pragma unroll
            for (int i = 0; i < 36; ++i) Hm2[i] = qt2[i];   // {Q/8, 0}
        }
        v2f sl2 = splat2(0.0f);
        v2f rp2[8];
        float rp16, rp17;
        // ---- loop A: rp + Hm (paired)
        PSTEPA(0, 2, g0)  PSTEPA(1, 2, g1)
        PSTEPA(2, 4, g2r) PSTEPA(3, 4, g3r)
        PSTEPA(4, 6, g4r) PSTEPA(5, 6, g5r)
        { LOADP(gv, 0) PSTEPA(6, 8, gv) }
        { LOADP(gv, 1) PSTEPA(7, 8, gv) }
        // ---- identity slots 16 (rows 0..7) and 17 (rows 8,9 on lanes 0,1)
        float w16, w17, sl_s;
        {
            float zs = z[0];
            #pragma unroll
            for (int i = 1; i < 8; ++i) zs = (lg == i) ? z[i] : zs;
            rp16 = zs + s16v - h16;
            sl_s = s16v * lam16v;
            w16 = lam16v * frcp(s16v);
            float zs17 = (lg == 1) ? z[9] : z[8];
            rp17 = zs17 + s17v - h17;
            sl_s = fmaf(s17v, lam17v, sl_s);
            w17 = lam17v * frcp(s17v);
        }
        // ---- fold pairs -> scalar, add identity diag, DPP 8-lane all-reduce
        float Hm[55];
        #pragma unroll
        for (int i = 0; i < 36; ++i) Hm[i] = Hm2[i].x + Hm2[i].y;
        #pragma unroll
        for (int i = 0; i < 8; ++i) Hm[TIX(i,i)] += (lg == i) ? w16 : 0.0f;
        float d88 = (lg == 0) ? w17 : 0.0f;
        float d99 = (lg == 1) ? w17 : 0.0f;
        float sl = sl2.x + sl2.y + sl_s;
        #pragma unroll
        for (int i = 0; i < 36; ++i) Hm[i] = red8_add(Hm[i]);
        d88 = red8_add(d88);
        d99 = red8_add(d99);
        sl = red8_add(sl);
        float smu = SIGMA_C * sl * (1.0f/138.0f);
        __asm__ __volatile__("" ::: "memory");   // keep B=8 LDS G-rows transient
        // ---- loop B: racc = sum_k g_k*(lam_k*rp_k+smu)/s_k (paired, .x=even .y=odd)
        v2f smu2 = splat2(smu);
        v2f racc2[8];
        #pragma unroll
        for (int i = 0; i < 8; ++i) racc2[i] = splat2(0.0f);
        PSTEPB(0, 2, g0)  PSTEPB(1, 2, g1)
        PSTEPB(2, 4, g2r) PSTEPB(3, 4, g3r)
        PSTEPB(4, 6, g4r) PSTEPB(5, 6, g5r)
        { LOADP(gv, 0) PSTEPB(6, 8, gv) }
        { LOADP(gv, 1) PSTEPB(7, 8, gv) }
        float coef16 = frcp(s16v) * fmaf(lam16v, rp16, smu);
        float coef17 = frcp(s17v) * fmaf(lam17v, rp17, smu);
        coef17 = (lg < 2) ? coef17 : 0.0f;
        float rs[10];
        #pragma unroll
        for (int i = 0; i < 8; ++i){
            float v = racc2[i].x + racc2[i].y;
            v += (lg == i) ? coef16 : 0.0f;
            rs[i] = red8_add(v);
        }
        rs[8] = red8_add((lg == 0) ? coef17 : 0.0f);
        rs[9] = red8_add((lg == 1) ? coef17 : 0.0f);
        // ---- rhs = -(p + racc) - Q z (packed Q-pass); rows 8,9 of H assigned
        v2f rhs2[5];
        {
            const float4* pv4 = (const float4*)(sPV + eidx*12);
            float4 pa = pv4[0], pb = pv4[1];
            const float2* pv2 = (const float2*)(sPV + eidx*12 + 8);
            float2 pc = pv2[0];
            rhs2[0] = make2(-(pa.x + rs[0]), -(pa.y + rs[1]));
            rhs2[1] = make2(-(pa.z + rs[2]), -(pa.w + rs[3]));
            rhs2[2] = make2(-(pb.x + rs[4]), -(pb.y + rs[5]));
            rhs2[3] = make2(-(pb.z + rs[6]), -(pb.w + rs[7]));
            rhs2[4] = make2(-(pc.x + rs[8]), -(pc.y + rs[9]));
        }
        #pragma unroll
        for (int j = 0; j < 10; ++j){
            float4 qa = sQm4[j*3+0], qb = sQm4[j*3+1], qc = sQm4[j*3+2];
            v2f mz = splat2(-z[j]);
            rhs2[0] = pkfma(mz, make2(qa.x, qa.y), rhs2[0]);
            rhs2[1] = pkfma(mz, make2(qa.z, qa.w), rhs2[1]);
            rhs2[2] = pkfma(mz, make2(qb.x, qb.y), rhs2[2]);
            rhs2[3] = pkfma(mz, make2(qb.z, qb.w), rhs2[3]);
            rhs2[4] = pkfma(mz, make2(qc.x, qc.y), rhs2[4]);
            if (j >= 8){
                float q[10] = {qa.x,qa.y,qa.z,qa.w, qb.x,qb.y,qb.z,qb.w, qc.x,qc.y};
                #pragma unroll
                for (int i = 0; i <= j; ++i) Hm[TIX(j,i)] = q[i];
            }
        }
        Hm[TIX(8,8)] += d88;
        Hm[TIX(9,9)] += d99;
        float rhs[10] = {rhs2[0].x, rhs2[0].y, rhs2[1].x, rhs2[1].y, rhs2[2].x,
                         rhs2[2].y, rhs2[3].x, rhs2[3].y, rhs2[4].x, rhs2[4].y};
        // ---- Cholesky (reciprocal diag in place)
        #pragma unroll
        for (int j = 0; j < 10; ++j){
            float d = Hm[TIX(j,j)];
            #pragma unroll
            for (int k2 = 0; k2 < j; ++k2){ float v = Hm[TIX(j,k2)]; d = fmaf(-v, v, d); }
            d = fmaxf(d, 1e-30f);
            float rinv = frsq(d);
            Hm[TIX(j,j)] = rinv;
            #pragma unroll
            for (int i = j+1; i < 10; ++i){
                float v2 = Hm[TIX(i,j)];
                #pragma unroll
                for (int k2 = 0; k2 < j; ++k2) v2 = fmaf(-Hm[TIX(i,k2)], Hm[TIX(j,k2)], v2);
                Hm[TIX(i,j)] = v2 * rinv;
            }
        }
        #pragma unroll
        for (int i = 0; i < 10; ++i){
            float v2 = rhs[i];
            #pragma unroll
            for (int k2 = 0; k2 < i; ++k2) v2 = fmaf(-Hm[TIX(i,k2)], rhs[k2], v2);
            rhs[i] = v2 * Hm[TIX(i,i)];
        }
        float dz[10];
        #pragma unroll
        for (int i = 9; i >= 0; --i){
            float v2 = rhs[i];
            #pragma unroll
            for (int k2 = i+1; k2 < 10; ++k2) v2 = fmaf(-Hm[TIX(k2,i)], dz[k2], v2);
            dz[i] = v2 * Hm[TIX(i,i)];
        }
        __asm__ __volatile__("" ::: "memory");
        // ---- loop C: steps + alpha (paired; max-of-inverse-ratios)
        v2f nsmu2 = splat2(-smu);
        v2f ds2[8], dl2[8];
        v2f av2 = splat2(0.0f);
        PSTEPC(0, 2, g0)  PSTEPC(1, 2, g1)
        PSTEPC(2, 4, g2r) PSTEPC(3, 4, g3r)
        PSTEPC(4, 6, g4r) PSTEPC(5, 6, g5r)
        { LOADP(gv, 0) PSTEPC(6, 8, gv) }
        { LOADP(gv, 1) PSTEPC(7, 8, gv) }
        float ds16, dl16, ds17, dl17;
        float ainv = fmaxf(av2.x, av2.y);
        {
            float dzs = dz[0];
            #pragma unroll
            for (int i = 1; i < 8; ++i) dzs = (lg == i) ? dz[i] : dzs;
            float dsk = -rp16 - dzs;
            float isk = frcp(s16v);
            float rc = fmaf(s16v, lam16v, -smu);
            float dlk = -(rc + lam16v * dsk) * isk;
            ds16 = dsk; dl16 = dlk;
            ainv = fmaxf(ainv, fmaxf(-dsk * isk, -dlk * frcp(lam16v)));
        }
        {
            float dzs = (lg == 1) ? dz[9] : dz[8];
            bool val = lg < 2;
            float dsk = val ? (-rp17 - dzs) : 0.0f;
            float isk = frcp(s17v);
            float rc = fmaf(s17v, lam17v, -smu);
            float dlk = -(rc + lam17v * dsk) * isk;
            dlk = val ? dlk : 0.0f;
            ds17 = dsk; dl17 = dlk;
            float cand = fmaxf(-dsk * isk, -dlk * frcp(lam17v));
            ainv = fmaxf(ainv, val ? cand : 0.0f);
        }
        ainv = red8_max(ainv);
        float alpha = fminf(1.0f, 0.99f * frcp(fmaxf(ainv, 1e-30f)));
        // ---- updates (packed s/lam)
        v2f al2 = splat2(alpha);
        #pragma unroll
        for (int i = 0; i < 10; ++i) z[i] = fmaf(alpha, dz[i], z[i]);
        #pragma unroll
        for (int p = 0; p < 8; ++p){
            s2[p]   = pkfma(al2, ds2[p], s2[p]);
            lam2[p] = pkfma(al2, dl2[p], lam2[p]);
        }
        s16v   = fmaf(alpha, ds16, s16v);
        s17v   = fmaf(alpha, ds17, s17v);
        lam16v = fmaf(alpha, dl16, lam16v);
        lam17v = fmaf(alpha, dl17, lam17v);
    }
    if (lg == 0) out[elem] = z[0];
}

extern "C" void kernel_launch(void* const* d_in, const int* in_sizes, int n_in,
                              void* d_out, int out_size, void* d_ws, size_t ws_size,
                              hipStream_t stream){
    const float* x   = (const float*)d_in[0];
    const float* w1  = (const float*)d_in[1];
    const float* b1  = (const float*)d_in[2];
    const float* w2  = (const float*)d_in[3];
    const float* b2  = (const float*)d_in[4];
    const float* g1  = (const float*)d_in[5];
    const float* bb1 = (const float*)d_in[6];
    const float* g2  = (const float*)d_in[7];
    const float* bb2 = (const float*)d_in[8];
    const float* L   = (const float*)d_in[9];
    const float* LP  = (const float*)d_in[10];
    const float* LR  = (const float*)d_in[11];
    const float* A   = (const float*)d_in[12];
    const float* Bm  = (const float*)d_in[13];
    const float* u0  = (const float*)d_in[14];
    const float* s0  = (const float*)d_in[15];
    float* ws  = (float*)d_ws;
    float* out = (float*)d_out;

    // zero P2 + P1 partial accumulators (floats 2048..10560)
    hipMemsetAsync(ws + P2_OFF, 0, (P1Q_OFF + 4096 - P2_OFF) * sizeof(float), stream);
    hipLaunchKernelGGL(k_buildstats, dim3(513), dim3(256), 0, stream,
                       L, LP, LR, A, Bm, u0, s0, x, w1, b1, ws);
    hipLaunchKernelGGL(k_fc2, dim3(256), dim3(512), 0, stream, x, w1, w2, b1, b2, g1, bb1, ws);
    hipLaunchKernelGGL(k_ipm, dim3(2048), dim3(64), 0, stream, ws, g2, bb2, out);
}

// Round 4
// 351.682 us; speedup vs baseline: 1.1486x; 1.0212x over previous
//
#include <hip/hip_runtime.h>
#include <math.h>

#define NIx 32
#define NOx 2
#define NUx 10
#define NHx 1024
#define NBx 16384
#define MIx 138
#define EPSQ 1e-4f
#define BNEPS 1e-5f
#define ITERS 30
#define SLOPE 0.2f
#define SIGMA_C 0.1f

// workspace layout (float offsets). Max = 174400 floats = 697.6 KB (< proven 723 KB).
#define QM_OFF 0        // 120 (pad 128)
#define G_OFF 128       // 144 x 12 -> 1856
#define H_OFF 1856      // 144 (pad 2048)
#define P2_OFF 2048     // 16 bufs x 20 (sum[10],sq[10]) = 320 (pad 2368)
#define P1S_OFF 2368    // 4 bufs x 1024 col-sums
#define P1Q_OFF 6464    // 4 bufs x 1024 col-sumsq -> 10560
#define PRAW_OFF 10560  // 16384 x 10 -> 174400
// memset zeroes [P2_OFF, P1Q_OFF+4096) = floats 2048..10560

__device__ __forceinline__ float frcp(float x){ return __builtin_amdgcn_rcpf(x); }
__device__ __forceinline__ float frsq(float x){ return __builtin_amdgcn_rsqf(x); }
__device__ __forceinline__ float lrelu(float x){ return x > 0.0f ? x : SLOPE * x; }

// packed fp32 helpers. NOTE (round-1 measurement): v_pk_*_f32 is issue-NEUTRAL on
// gfx950. Kept because the pairing structure organizes the code.
typedef float v2f __attribute__((ext_vector_type(2)));
__device__ __forceinline__ v2f make2(float a, float b){ v2f r; r.x = a; r.y = b; return r; }
__device__ __forceinline__ v2f splat2(float a){ v2f r; r.x = a; r.y = a; return r; }
__device__ __forceinline__ v2f pkfma(v2f a, v2f b, v2f c){ return __builtin_elementwise_fma(a, b, c); }
__device__ __forceinline__ v2f pkmax(v2f a, v2f b){ return __builtin_elementwise_max(a, b); }

// ---- DPP cross-lane reductions (VALU, no LDS pipe) ----
template<int CTRL>
__device__ __forceinline__ float dpp_mov(float x){
    int y = __builtin_amdgcn_update_dpp(0, __float_as_int(x), CTRL, 0xF, 0xF, true);
    return __int_as_float(y);
}
// 8-lane all-reduce: xor1 (quad_perm[1,0,3,2]), xor2 (quad_perm[2,3,0,1]),
// then row_half_mirror (0x141: i -> 7-i within each 8 = xor-7) closes the group.
__device__ __forceinline__ float red8_add(float x){
    x += dpp_mov<0xB1>(x);
    x += dpp_mov<0x4E>(x);
    x += dpp_mov<0x141>(x);
    return x;
}
__device__ __forceinline__ float red8_max(float x){
    x = fmaxf(x, dpp_mov<0xB1>(x));
    x = fmaxf(x, dpp_mov<0x4E>(x));
    x = fmaxf(x, dpp_mov<0x141>(x));
    return x;
}

// ---------- merged: blocks 0..511 BN1-stats, block 512 QP-build (independent work) ----------
// Round-14: BN1 path stages its 128 x-rows in LDS (coalesced float4 vector loads),
// inner loop reads x as wave-uniform broadcast ds_read_b128 instead of the
// s_load/L2-latency chain (theory: operand-fetch latency, not VALU, dominates —
// evidenced by r1's -59us from w1 scalarization being the only non-null change).
__global__ __launch_bounds__(256) void k_buildstats(const float* L, const float* LP, const float* LR,
                                                    const float* A, const float* Bm,
                                                    const float* u0, const float* s0,
                                                    const float* x, const float* w1, const float* b1,
                                                    float* ws){
    __shared__ float sL[1024], sLP[1024], sA[1024], sQ[1024], sP[1024];
    __shared__ float sPow[4][64];
    __shared__ float sBh[128*10];
    __shared__ float sQB[128*10];
    __shared__ float sR[3];
    __shared__ __align__(16) float sX[4096];   // 128 x-rows, 16 KB (BN1 path only)
    int t = threadIdx.x;
    if (blockIdx.x < 512){
        // ---- BN1 stats path: partial col sum/sumsq into 4 spread buffers ----
        int rb = blockIdx.x >> 2;        // 128 row-groups of 128 rows
        int cb = blockIdx.x & 3;         // 4 col-groups of 256 cols
        int c = cb * 256 + t;
        const float4* wg4 = (const float4*)(w1 + (size_t)c * 32);
        float4 wr[8];
        #pragma unroll
        for (int q = 0; q < 8; ++q) wr[q] = wg4[q];
        float bc = b1[c];
        int r0 = rb * 128;
        // stage x rows r0..r0+127 (coalesced: 1024 float4 over 256 threads)
        const float4* xg4 = (const float4*)x + (size_t)r0 * 8;
        float4* sX4 = (float4*)sX;
        #pragma unroll
        for (int idx = t; idx < 1024; idx += 256) sX4[idx] = xg4[idx];
        __syncthreads();
        float sum = 0.0f, sq = 0.0f;
        #pragma unroll 2
        for (int r = 0; r < 128; ++r){
            const float4* xr4 = sX4 + r * 8;   // wave-uniform -> broadcast ds_read_b128
            float a0 = 0, a1 = 0, a2 = 0, a3 = 0;
            #pragma unroll
            for (int q = 0; q < 8; ++q){
                float4 v = xr4[q];
                a0 = fmaf(v.x, wr[q].x, a0);
                a1 = fmaf(v.y, wr[q].y, a1);
                a2 = fmaf(v.z, wr[q].z, a2);
                a3 = fmaf(v.w, wr[q].w, a3);
            }
            float h = lrelu((a0 + a1) + (a2 + a3) + bc);
            sum += h; sq = fmaf(h, h, sq);
        }
        int buf = (rb & 3) * 1024 + c;
        atomicAdd(&ws[P1S_OFF + buf], sum);
        atomicAdd(&ws[P1Q_OFF + buf], sq);
        return;
    }
    // ---- QP build path (single block) ----
    for (int idx = t; idx < 1024; idx += 256){
        int i = idx >> 5, j = idx & 31;
        sL[idx]  = (j <= i) ? L[idx]  : 0.0f;
        sLP[idx] = (j <= i) ? LP[idx] : 0.0f;
        sA[idx]  = A[idx];
    }
    if (t < 64) sPow[0][t] = Bm[t];
    if (t == 0){
        float a = LR[0], b = LR[2], c = LR[3];   // tril: [[a,0],[b,c]]
        sR[0] = a*a + EPSQ; sR[1] = a*b; sR[2] = b*b + c*c + EPSQ;
    }
    __syncthreads();
    for (int idx = t; idx < 1024; idx += 256){
        int i = idx >> 5, j = idx & 31;
        float q = 0.0f, p = 0.0f;
        for (int k = 0; k < 32; ++k){
            q = fmaf(sL[i*32+k],  sL[j*32+k],  q);
            p = fmaf(sLP[i*32+k], sLP[j*32+k], p);
        }
        if (i == j){ q += EPSQ; p += EPSQ; }
        sQ[idx] = q; sP[idx] = p;
    }
    for (int kp = 1; kp < 4; ++kp){
        __syncthreads();
        if (t < 64){
            int i = t >> 1, c = t & 1;
            float a = 0.0f;
            for (int j = 0; j < 32; ++j) a = fmaf(sA[i*32+j], sPow[kp-1][j*2+c], a);
            sPow[kp][t] = a;
        }
    }
    __syncthreads();
    for (int idx = t; idx < 1280; idx += 256){
        int r = idx / 10, c = idx % 10;
        int bi = r >> 5, ri = r & 31, bj = c >> 1, cj = c & 1;
        sBh[idx] = (bj <= bi) ? sPow[bi-bj][ri*2+cj] : 0.0f;
    }
    __syncthreads();
    for (int idx = t; idx < 1280; idx += 256){
        int r = idx / 10, c = idx % 10;
        int bi = r >> 5, ri = r & 31;
        const float* Qd = (bi < 3) ? sQ : sP;
        float a = 0.0f;
        for (int k = 0; k < 32; ++k) a = fmaf(Qd[ri*32+k], sBh[(bi*32+k)*10+c], a);
        sQB[idx] = a;
    }
    __syncthreads();
    if (t < 120){
        int i = t / 12, j = t % 12;
        float a = 0.0f;
        if (j < 10){
            for (int r = 0; r < 128; ++r) a = fmaf(sBh[r*10+i], sQB[r*10+j], a);
            if ((i >> 1) == (j >> 1)) a += sR[(i&1)+(j&1)];
        }
        ws[QM_OFF + t] = a;
    }
    for (int idx = t; idx < 144*12; idx += 256){
        int m = idx / 12, i = idx % 12;
        float v = 0.0f;
        if (i < 10 && m < MIx) v = (m < 10) ? ((i == m) ? 1.0f : 0.0f) : sBh[(m-10)*10 + i];
        ws[G_OFF + idx] = v;
    }
    for (int m = t; m < 144; m += 256){
        float hv = 0.0f;
        if (m < MIx){
            hv = s0[m];
            if (m < 10) hv += u0[m];
            else { for (int i = 0; i < 10; ++i) hv = fmaf(sBh[(m-10)*10+i], u0[i], hv); }
        }
        ws[H_OFF + m] = hv;
    }
}

// ---------- fc2 with BN1-finalize folded in-block ----------
// Round-14: w1 consumed from LDS in 8 cooperatively-staged 16 KB k-chunks
// (coalesced float4 global loads; wave-uniform broadcast ds_read_b128 inside the
// k-loop) instead of 8 s_load_dwordx4/iter from L2. Each wave consumes its own
// 16-row slice of the current chunk. pacc aliases the chunk buffer
// (barrier-separated). w2/b1 scalar loads kept (proven non-bottleneck r3).
__global__ __launch_bounds__(512) void k_fc2(const float* __restrict__ x, const float* __restrict__ w1,
                                             const float* __restrict__ w2, const float* __restrict__ b1v,
                                             const float* __restrict__ b2v, const float* __restrict__ g1,
                                             const float* __restrict__ bb1, float* __restrict__ ws){
    __shared__ __align__(16) float sPool[5120];  // chunks: sW 4096 floats; after: pacc 5120
    __shared__ float sA1[1024], sC1[1024];
    int t = threadIdx.x;
    #pragma unroll
    for (int k = t; k < 1024; k += 512){
        float ssum = 0.0f, qsum = 0.0f;
        #pragma unroll
        for (int b = 0; b < 4; ++b){
            ssum += ws[P1S_OFF + b*1024 + k];
            qsum += ws[P1Q_OFF + b*1024 + k];
        }
        float mu  = ssum * (1.0f/16384.0f);
        float var = qsum * (1.0f/16384.0f) - mu*mu;
        float a1 = g1[k] / sqrtf(var + BNEPS);
        sA1[k] = a1;
        sC1[k] = bb1[k] - mu * a1;
    }
    int r = t & 63;
    int q = t >> 6;                  // 0..7: wave owns a 16-row slice of each chunk
    int row = blockIdx.x * 64 + r;
    const float4* xg4 = (const float4*)(x + (size_t)row * 32);
    float4 xr[8];
    #pragma unroll
    for (int i = 0; i < 8; ++i) xr[i] = xg4[i];
    float acc[10];
    #pragma unroll
    for (int j = 0; j < 10; ++j) acc[j] = 0.0f;
    const float4* w1g4 = (const float4*)w1;
    float4* sW4 = (float4*)sPool;
    for (int ch = 0; ch < 8; ++ch){
        __syncthreads();   // previous chunk fully consumed (also fences sA1/sC1 on ch=0)
        #pragma unroll
        for (int idx = t; idx < 1024; idx += 512) sW4[idx] = w1g4[ch*1024 + idx];
        __syncthreads();
        #pragma unroll
        for (int i = 0; i < 16; ++i){
            int klc = __builtin_amdgcn_readfirstlane(q*16 + i);      // chunk-local row
            int kl  = __builtin_amdgcn_readfirstlane(ch*128 + klc);  // global k
            const float4* wv4 = sW4 + klc*8;   // wave-uniform -> broadcast ds_read_b128
            float a0 = 0, a1 = 0, a2 = 0, a3 = 0;
            #pragma unroll
            for (int u = 0; u < 8; ++u){
                float4 wv = wv4[u];
                float4 xv = xr[u];
                a0 = fmaf(xv.x, wv.x, a0);
                a1 = fmaf(xv.y, wv.y, a1);
                a2 = fmaf(xv.z, wv.z, a2);
                a3 = fmaf(xv.w, wv.w, a3);
            }
            float h = fmaf(lrelu((a0 + a1) + (a2 + a3) + b1v[kl]), sA1[kl], sC1[kl]);
            #pragma unroll
            for (int j = 0; j < 10; ++j) acc[j] = fmaf(h, w2[j*1024 + kl], acc[j]);
        }
    }
    __syncthreads();   // all waves done with sW before pacc aliases the region
    float* pacc = sPool;
    #pragma unroll
    for (int j = 0; j < 10; ++j) pacc[t*10 + j] = acc[j];
    __syncthreads();
    if (t < 64){
        float pv[10];
        #pragma unroll
        for (int j = 0; j < 10; ++j){
            float a = b2v[j];
            #pragma unroll
            for (int w = 0; w < 8; ++w) a += pacc[(w*64 + t)*10 + j];
            pv[j] = lrelu(a);
        }
        #pragma unroll
        for (int j = 0; j < 10; ++j) ws[PRAW_OFF + (size_t)(blockIdx.x*64 + t)*10 + j] = pv[j];
        float sv[10], qv[10];
        #pragma unroll
        for (int j = 0; j < 10; ++j){ sv[j] = pv[j]; qv[j] = pv[j]*pv[j]; }
        #pragma unroll
        for (int m = 1; m < 64; m <<= 1){
            #pragma unroll
            for (int j = 0; j < 10; ++j){
                sv[j] += __shfl_xor(sv[j], m);
                qv[j] += __shfl_xor(qv[j], m);
            }
        }
        if (t == 0){
            int base = P2_OFF + (blockIdx.x & 15) * 20;
            #pragma unroll
            for (int j = 0; j < 10; ++j){
                atomicAdd(&ws[base + j], sv[j]);
                atomicAdd(&ws[base + 10 + j], qv[j]);
            }
        }
    }
}

// ---------- batched IPM: 8 lanes/element, 8 elements per 64-thread block ----------
// Round-11 structure (REVERTED round-12's register promotion: allocator hard-caps
// this kernel at 128 VGPR — promoting g6/g7/hh/isv spilled to scratch, 137 MB
// of WRITE_SIZE, +41 us. 128-VGPR envelope is the law here.)
//   16 B_hat slots paired into v2f; G pairs B=2/4/6 in registers; B=8 pairs in
//   LDS (pair-packed, stride 36); h pairs in LDS; rp in registers.
#define TIX(i,j) ((i)*((i)+1)/2 + (j))

#define PSTEPA(P, B, GP) { \
    v2f sv = s2[P], lv = lam2[P]; \
    v2f isv; isv.x = frcp(sv.x); isv.y = frcp(sv.y); \
    v2f wv = lv * isv; \
    v2f r = sv - *(const v2f*)(sHH2 + (P)*16 + lg*2); \
    _Pragma("unroll") \
    for (int _i = 0; _i < (B); ++_i) r = pkfma(splat2(z[_i]), GP[_i], r); \
    rp2[P] = r; \
    sl2 = pkfma(sv, lv, sl2); \
    _Pragma("unroll") \
    for (int _i = 0; _i < (B); ++_i){ \
        v2f wg = wv * GP[_i]; \
        _Pragma("unroll") \
        for (int _j = 0; _j <= _i; ++_j) Hm2[TIX(_i,_j)] = pkfma(wg, GP[_j], Hm2[TIX(_i,_j)]); \
    } }

#define PSTEPB(P, B, GP) { \
    v2f sv = s2[P], lv = lam2[P]; \
    v2f isv; isv.x = frcp(sv.x); isv.y = frcp(sv.y); \
    v2f coef = pkfma(lv, rp2[P], smu2) * isv; \
    _Pragma("unroll") \
    for (int _i = 0; _i < (B); ++_i) racc2[_i] = pkfma(coef, GP[_i], racc2[_i]); }

#define PSTEPC(P, B, GP) { \
    v2f dotv = splat2(0.0f); \
    _Pragma("unroll") \
    for (int _i = 0; _i < (B); ++_i) dotv = pkfma(splat2(dz[_i]), GP[_i], dotv); \
    v2f sv = s2[P], lv = lam2[P]; \
    v2f isv; isv.x = frcp(sv.x); isv.y = frcp(sv.y); \
    v2f dsv = -(rp2[P] + dotv); \
    v2f rcv = pkfma(sv, lv, nsmu2); \
    v2f dlv = -(pkfma(lv, dsv, rcv) * isv); \
    ds2[P] = dsv; dl2[P] = dlv; \
    v2f ilv; ilv.x = frcp(lv.x); ilv.y = frcp(lv.y); \
    av2 = pkmax(av2, pkmax((-dsv)*isv, (-dlv)*ilv)); }

#define LOADP(GP, PP) v2f GP[8]; { \
    const float4* _g4 = (const float4*)(sG3 + lg*36 + (PP)*16); \
    float4 _a = _g4[0], _b = _g4[1], _c = _g4[2], _d = _g4[3]; \
    GP[0] = make2(_a.x,_a.y); GP[1] = make2(_a.z,_a.w); \
    GP[2] = make2(_b.x,_b.y); GP[3] = make2(_b.z,_b.w); \
    GP[4] = make2(_c.x,_c.y); GP[5] = make2(_c.z,_c.w); \
    GP[6] = make2(_d.x,_d.y); GP[7] = make2(_d.z,_d.w); }

__global__ __launch_bounds__(64, 2) void k_ipm(const float* __restrict__ ws, const float* __restrict__ g2v,
                                               const float* __restrict__ bb2, float* __restrict__ out){
    __shared__ __align__(16) float sQm[120];
    __shared__ __align__(16) float sQt2[72];    // {Q/8, 0} interleaved, tri rows 0..7
    __shared__ __align__(16) float sPV[8*12];
    __shared__ __align__(16) float sG3[8*36];   // B=8 G pairs, pair-packed per lg
    __shared__ __align__(16) float sHH2[128];   // h pair-packed: [p*16 + lg*2 + c]
    __shared__ float sA2[10], sC2[10];
    int t = threadIdx.x;
    for (int i = t; i < 120; i += 64) sQm[i] = ws[QM_OFF + i];
    if (t < 36){
        int i = 0;
        #pragma unroll
        for (int r = 1; r < 8; ++r) if (TIX(r,0) <= t) i = r;
        int j = t - TIX(i,0);
        sQt2[t*2]   = ws[QM_OFF + i*12 + j] * 0.125f;
        sQt2[t*2+1] = 0.0f;
    }
    if (t < 10){   // BN2 finalize (redundant per block — trivial)
        float ssum = 0.0f, qsum = 0.0f;
        #pragma unroll
        for (int b = 0; b < 16; ++b){
            ssum += ws[P2_OFF + b*20 + t];
            qsum += ws[P2_OFF + b*20 + 10 + t];
        }
        float mu  = ssum * (1.0f/16384.0f);
        float var = qsum * (1.0f/16384.0f) - mu*mu;
        float a2 = g2v[t] / sqrtf(var + BNEPS);
        sA2[t] = a2;
        sC2[t] = bb2[t] - mu * a2;
    }
    __syncthreads();

    int lg = t & 7;
    int eidx = t >> 3;
    int elem = blockIdx.x * 8 + eidx;
    const float* GB = ws + G_OFF;
    const float4* sQm4 = (const float4*)sQm;

    for (int i = t; i < 80; i += 64){
        int e = i / 10, c = i - e*10;
        int el = blockIdx.x * 8 + e;
        sPV[e*12 + c] = fmaf(ws[PRAW_OFF + (size_t)el*10 + c], sA2[c], sC2[c]);
    }
    // h pair-packed: pair p covers slots 2p,2p+1 (block b=p>>1, k&3 = 2(p&1)+c)
    for (int i = t; i < 128; i += 64){
        int c = i & 1, lgx = (i >> 1) & 7, p = i >> 4;
        int row = 10 + (p >> 1)*32 + (2*(p & 1) + c)*8 + lgx;
        sHH2[p*16 + lgx*2 + c] = ws[H_OFF + row];
    }
    // B=8 pairs (slots 12..15) pair-packed in LDS: sG3[lg*36 + pp*16 + i*2 + c]
    for (int i = t; i < 256; i += 64){
        int c = i & 1, ii = (i >> 1) & 7, pp = (i >> 4) & 1, lgx = i >> 5;
        int row = 106 + (pp*2 + c)*8 + lgx;
        sG3[lgx*36 + pp*16 + ii*2 + c] = GB[row*12 + ii];
    }
    // register-resident G pairs (B=2,4,6): gp[i] = {G[row_a,i], G[row_b,i]}
    v2f g0[2], g1[2], g2r[4], g3r[4], g4r[6], g5r[6];
    {
        int ra, rb;
        ra = 10 + lg; rb = 18 + lg;
        #pragma unroll
        for (int i = 0; i < 2; ++i) g0[i] = make2(GB[ra*12+i], GB[rb*12+i]);
        ra = 26 + lg; rb = 34 + lg;
        #pragma unroll
        for (int i = 0; i < 2; ++i) g1[i] = make2(GB[ra*12+i], GB[rb*12+i]);
        ra = 42 + lg; rb = 50 + lg;
        #pragma unroll
        for (int i = 0; i < 4; ++i) g2r[i] = make2(GB[ra*12+i], GB[rb*12+i]);
        ra = 58 + lg; rb = 66 + lg;
        #pragma unroll
        for (int i = 0; i < 4; ++i) g3r[i] = make2(GB[ra*12+i], GB[rb*12+i]);
        ra = 74 + lg; rb = 82 + lg;
        #pragma unroll
        for (int i = 0; i < 6; ++i) g4r[i] = make2(GB[ra*12+i], GB[rb*12+i]);
        ra = 90 + lg; rb = 98 + lg;
        #pragma unroll
        for (int i = 0; i < 6; ++i) g5r[i] = make2(GB[ra*12+i], GB[rb*12+i]);
    }
    float h16 = ws[H_OFF + lg];                          // identity rows 0..7
    float h17 = (lg < 2) ? ws[H_OFF + 8 + lg] : 1.0f;    // identity rows 8,9
    __syncthreads();

    float z[10];
    #pragma unroll
    for (int i = 0; i < 10; ++i) z[i] = 0.0f;
    v2f s2[8], lam2[8];
    #pragma unroll
    for (int p = 0; p < 8; ++p){ s2[p] = splat2(1.0f); lam2[p] = splat2(1.0f); }
    float s16v = 1.0f, s17v = 1.0f, lam16v = 1.0f;
    float lam17v = (lg < 2) ? 1.0f : 0.0f;

    #pragma unroll 1
    for (int it = 0; it < ITERS; ++it){
        v2f Hm2[36];
        {
            const v2f* qt2 = (const v2f*)sQt2;
            #pragma unroll
            for (int i = 0; i < 36; ++i) Hm2[i] = qt2[i];   // {Q/8, 0}
        }
        v2f sl2 = splat2(0.0f);
        v2f rp2[8];
        float rp16, rp17;
        // ---- loop A: rp + Hm (paired)
        PSTEPA(0, 2, g0)  PSTEPA(1, 2, g1)
        PSTEPA(2, 4, g2r) PSTEPA(3, 4, g3r)
        PSTEPA(4, 6, g4r) PSTEPA(5, 6, g5r)
        { LOADP(gv, 0) PSTEPA(6, 8, gv) }
        { LOADP(gv, 1) PSTEPA(7, 8, gv) }
        // ---- identity slots 16 (rows 0..7) and 17 (rows 8,9 on lanes 0,1)
        float w16, w17, sl_s;
        {
            float zs = z[0];
            #pragma unroll
            for (int i = 1; i < 8; ++i) zs = (lg == i) ? z[i] : zs;
            rp16 = zs + s16v - h16;
            sl_s = s16v * lam16v;
            w16 = lam16v * frcp(s16v);
            float zs17 = (lg == 1) ? z[9] : z[8];
            rp17 = zs17 + s17v - h17;
            sl_s = fmaf(s17v, lam17v, sl_s);
            w17 = lam17v * frcp(s17v);
        }
        // ---- fold pairs -> scalar, add identity diag, DPP 8-lane all-reduce
        float Hm[55];
        #pragma unroll
        for (int i = 0; i < 36; ++i) Hm[i] = Hm2[i].x + Hm2[i].y;
        #pragma unroll
        for (int i = 0; i < 8; ++i) Hm[TIX(i,i)] += (lg == i) ? w16 : 0.0f;
        float d88 = (lg == 0) ? w17 : 0.0f;
        float d99 = (lg == 1) ? w17 : 0.0f;
        float sl = sl2.x + sl2.y + sl_s;
        #pragma unroll
        for (int i = 0; i < 36; ++i) Hm[i] = red8_add(Hm[i]);
        d88 = red8_add(d88);
        d99 = red8_add(d99);
        sl = red8_add(sl);
        float smu = SIGMA_C * sl * (1.0f/138.0f);
        __asm__ __volatile__("" ::: "memory");   // keep B=8 LDS G-rows transient
        // ---- loop B: racc = sum_k g_k*(lam_k*rp_k+smu)/s_k (paired, .x=even .y=odd)
        v2f smu2 = splat2(smu);
        v2f racc2[8];
        #pragma unroll
        for (int i = 0; i < 8; ++i) racc2[i] = splat2(0.0f);
        PSTEPB(0, 2, g0)  PSTEPB(1, 2, g1)
        PSTEPB(2, 4, g2r) PSTEPB(3, 4, g3r)
        PSTEPB(4, 6, g4r) PSTEPB(5, 6, g5r)
        { LOADP(gv, 0) PSTEPB(6, 8, gv) }
        { LOADP(gv, 1) PSTEPB(7, 8, gv) }
        float coef16 = frcp(s16v) * fmaf(lam16v, rp16, smu);
        float coef17 = frcp(s17v) * fmaf(lam17v, rp17, smu);
        coef17 = (lg < 2) ? coef17 : 0.0f;
        float rs[10];
        #pragma unroll
        for (int i = 0; i < 8; ++i){
            float v = racc2[i].x + racc2[i].y;
            v += (lg == i) ? coef16 : 0.0f;
            rs[i] = red8_add(v);
        }
        rs[8] = red8_add((lg == 0) ? coef17 : 0.0f);
        rs[9] = red8_add((lg == 1) ? coef17 : 0.0f);
        // ---- rhs = -(p + racc) - Q z (packed Q-pass); rows 8,9 of H assigned
        v2f rhs2[5];
        {
            const float4* pv4 = (const float4*)(sPV + eidx*12);
            float4 pa = pv4[0], pb = pv4[1];
            const float2* pv2 = (const float2*)(sPV + eidx*12 + 8);
            float2 pc = pv2[0];
            rhs2[0] = make2(-(pa.x + rs[0]), -(pa.y + rs[1]));
            rhs2[1] = make2(-(pa.z + rs[2]), -(pa.w + rs[3]));
            rhs2[2] = make2(-(pb.x + rs[4]), -(pb.y + rs[5]));
            rhs2[3] = make2(-(pb.z + rs[6]), -(pb.w + rs[7]));
            rhs2[4] = make2(-(pc.x + rs[8]), -(pc.y + rs[9]));
        }
        #pragma unroll
        for (int j = 0; j < 10; ++j){
            float4 qa = sQm4[j*3+0], qb = sQm4[j*3+1], qc = sQm4[j*3+2];
            v2f mz = splat2(-z[j]);
            rhs2[0] = pkfma(mz, make2(qa.x, qa.y), rhs2[0]);
            rhs2[1] = pkfma(mz, make2(qa.z, qa.w), rhs2[1]);
            rhs2[2] = pkfma(mz, make2(qb.x, qb.y), rhs2[2]);
            rhs2[3] = pkfma(mz, make2(qb.z, qb.w), rhs2[3]);
            rhs2[4] = pkfma(mz, make2(qc.x, qc.y), rhs2[4]);
            if (j >= 8){
                float q[10] = {qa.x,qa.y,qa.z,qa.w, qb.x,qb.y,qb.z,qb.w, qc.x,qc.y};
                #pragma unroll
                for (int i = 0; i <= j; ++i) Hm[TIX(j,i)] = q[i];
            }
        }
        Hm[TIX(8,8)] += d88;
        Hm[TIX(9,9)] += d99;
        float rhs[10] = {rhs2[0].x, rhs2[0].y, rhs2[1].x, rhs2[1].y, rhs2[2].x,
                         rhs2[2].y, rhs2[3].x, rhs2[3].y, rhs2[4].x, rhs2[4].y};
        // ---- Cholesky (reciprocal diag in place)
        #pragma unroll
        for (int j = 0; j < 10; ++j){
            float d = Hm[TIX(j,j)];
            #pragma unroll
            for (int k2 = 0; k2 < j; ++k2){ float v = Hm[TIX(j,k2)]; d = fmaf(-v, v, d); }
            d = fmaxf(d, 1e-30f);
            float rinv = frsq(d);
            Hm[TIX(j,j)] = rinv;
            #pragma unroll
            for (int i = j+1; i < 10; ++i){
                float v2 = Hm[TIX(i,j)];
                #pragma unroll
                for (int k2 = 0; k2 < j; ++k2) v2 = fmaf(-Hm[TIX(i,k2)], Hm[TIX(j,k2)], v2);
                Hm[TIX(i,j)] = v2 * rinv;
            }
        }
        #pragma unroll
        for (int i = 0; i < 10; ++i){
            float v2 = rhs[i];
            #pragma unroll
            for (int k2 = 0; k2 < i; ++k2) v2 = fmaf(-Hm[TIX(i,k2)], rhs[k2], v2);
            rhs[i] = v2 * Hm[TIX(i,i)];
        }
        float dz[10];
        #pragma unroll
        for (int i = 9; i >= 0; --i){
            float v2 = rhs[i];
            #pragma unroll
            for (int k2 = i+1; k2 < 10; ++k2) v2 = fmaf(-Hm[TIX(k2,i)], dz[k2], v2);
            dz[i] = v2 * Hm[TIX(i,i)];
        }
        __asm__ __volatile__("" ::: "memory");
        // ---- loop C: steps + alpha (paired; max-of-inverse-ratios)
        v2f nsmu2 = splat2(-smu);
        v2f ds2[8], dl2[8];
        v2f av2 = splat2(0.0f);
        PSTEPC(0, 2, g0)  PSTEPC(1, 2, g1)
        PSTEPC(2, 4, g2r) PSTEPC(3, 4, g3r)
        PSTEPC(4, 6, g4r) PSTEPC(5, 6, g5r)
        { LOADP(gv, 0) PSTEPC(6, 8, gv) }
        { LOADP(gv, 1) PSTEPC(7, 8, gv) }
        float ds16, dl16, ds17, dl17;
        float ainv = fmaxf(av2.x, av2.y);
        {
            float dzs = dz[0];
            #pragma unroll
            for (int i = 1; i < 8; ++i) dzs = (lg == i) ? dz[i] : dzs;
            float dsk = -rp16 - dzs;
            float isk = frcp(s16v);
            float rc = fmaf(s16v, lam16v, -smu);
            float dlk = -(rc + lam16v * dsk) * isk;
            ds16 = dsk; dl16 = dlk;
            ainv = fmaxf(ainv, fmaxf(-dsk * isk, -dlk * frcp(lam16v)));
        }
        {
            float dzs = (lg == 1) ? dz[9] : dz[8];
            bool val = lg < 2;
            float dsk = val ? (-rp17 - dzs) : 0.0f;
            float isk = frcp(s17v);
            float rc = fmaf(s17v, lam17v, -smu);
            float dlk = -(rc + lam17v * dsk) * isk;
            dlk = val ? dlk : 0.0f;
            ds17 = dsk; dl17 = dlk;
            float cand = fmaxf(-dsk * isk, -dlk * frcp(lam17v));
            ainv = fmaxf(ainv, val ? cand : 0.0f);
        }
        ainv = red8_max(ainv);
        float alpha = fminf(1.0f, 0.99f * frcp(fmaxf(ainv, 1e-30f)));
        // ---- updates (packed s/lam)
        v2f al2 = splat2(alpha);
        #pragma unroll
        for (int i = 0; i < 10; ++i) z[i] = fmaf(alpha, dz[i], z[i]);
        #pragma unroll
        for (int p = 0; p < 8; ++p){
            s2[p]   = pkfma(al2, ds2[p], s2[p]);
            lam2[p] = pkfma(al2, dl2[p], lam2[p]);
        }
        s16v   = fmaf(alpha, ds16, s16v);
        s17v   = fmaf(alpha, ds17, s17v);
        lam16v = fmaf(alpha, dl16, lam16v);
        lam17v = fmaf(alpha, dl17, lam17v);
    }
    if (lg == 0) out[elem] = z[0];
}

extern "C" void kernel_launch(void* const* d_in, const int* in_sizes, int n_in,
                              void* d_out, int out_size, void* d_ws, size_t ws_size,
                              hipStream_t stream){
    const float* x   = (const float*)d_in[0];
    const float* w1  = (const float*)d_in[1];
    const float* b1  = (const float*)d_in[2];
    const float* w2  = (const float*)d_in[3];
    const float* b2  = (const float*)d_in[4];
    const float* g1  = (const float*)d_in[5];
    const float* bb1 = (const float*)d_in[6];
    const float* g2  = (const float*)d_in[7];
    const float* bb2 = (const float*)d_in[8];
    const float* L   = (const float*)d_in[9];
    const float* LP  = (const float*)d_in[10];
    const float* LR  = (const float*)d_in[11];
    const float* A   = (const float*)d_in[12];
    const float* Bm  = (const float*)d_in[13];
    const float* u0  = (const float*)d_in[14];
    const float* s0  = (const float*)d_in[15];
    float* ws  = (float*)d_ws;
    float* out = (float*)d_out;

    // zero P2 + P1 partial accumulators (floats 2048..10560)
    hipMemsetAsync(ws + P2_OFF, 0, (P1Q_OFF + 4096 - P2_OFF) * sizeof(float), stream);
    hipLaunchKernelGGL(k_buildstats, dim3(513), dim3(256), 0, stream,
                       L, LP, LR, A, Bm, u0, s0, x, w1, b1, ws);
    hipLaunchKernelGGL(k_fc2, dim3(256), dim3(512), 0, stream, x, w1, w2, b1, b2, g1, bb1, ws);
    hipLaunchKernelGGL(k_ipm, dim3(2048), dim3(64), 0, stream, ws, g2, bb2, out);
}

// Round 5
// 307.722 us; speedup vs baseline: 1.3126x; 1.1429x over previous
//
#include <hip/hip_runtime.h>
#include <math.h>

#define NIx 32
#define NOx 2
#define NUx 10
#define NHx 1024
#define NBx 16384
#define MIx 138
#define EPSQ 1e-4f
#define BNEPS 1e-5f
#define ITERS 30
#define SLOPE 0.2f
#define SIGMA_C 0.1f

// workspace layout (float offsets). Max = 174400 floats = 697.6 KB (< proven 723 KB).
#define QM_OFF 0        // 120 (pad 128)
#define G_OFF 128       // 144 x 12 -> 1856
#define H_OFF 1856      // 144 (pad 2048)
#define P2_OFF 2048     // 16 bufs x 20 (sum[10],sq[10]) = 320 (pad 2368)
#define P1S_OFF 2368    // 4 bufs x 1024 col-sums
#define P1Q_OFF 6464    // 4 bufs x 1024 col-sumsq -> 10560
#define PRAW_OFF 10560  // 16384 x 10 -> 174400
// memset zeroes [P2_OFF, P1Q_OFF+4096) = floats 2048..10560

__device__ __forceinline__ float frcp(float x){ return __builtin_amdgcn_rcpf(x); }
__device__ __forceinline__ float frsq(float x){ return __builtin_amdgcn_rsqf(x); }
__device__ __forceinline__ float lrelu(float x){ return x > 0.0f ? x : SLOPE * x; }

// packed fp32 helpers. NOTE (round-1 measurement): v_pk_*_f32 is issue-NEUTRAL on
// gfx950. Kept because the pairing structure organizes the code.
typedef float v2f __attribute__((ext_vector_type(2)));
__device__ __forceinline__ v2f make2(float a, float b){ v2f r; r.x = a; r.y = b; return r; }
__device__ __forceinline__ v2f splat2(float a){ v2f r; r.x = a; r.y = a; return r; }
__device__ __forceinline__ v2f pkfma(v2f a, v2f b, v2f c){ return __builtin_elementwise_fma(a, b, c); }
__device__ __forceinline__ v2f pkmax(v2f a, v2f b){ return __builtin_elementwise_max(a, b); }

// ---- DPP cross-lane reductions (VALU, no LDS pipe) ----
template<int CTRL>
__device__ __forceinline__ float dpp_mov(float x){
    int y = __builtin_amdgcn_update_dpp(0, __float_as_int(x), CTRL, 0xF, 0xF, true);
    return __int_as_float(y);
}
// 8-lane all-reduce: xor1 (quad_perm[1,0,3,2]), xor2 (quad_perm[2,3,0,1]),
// then row_half_mirror (0x141: i -> 7-i within each 8 = xor-7) closes the group.
__device__ __forceinline__ float red8_add(float x){
    x += dpp_mov<0xB1>(x);
    x += dpp_mov<0x4E>(x);
    x += dpp_mov<0x141>(x);
    return x;
}
__device__ __forceinline__ float red8_max(float x){
    x = fmaxf(x, dpp_mov<0xB1>(x));
    x = fmaxf(x, dpp_mov<0x4E>(x));
    x = fmaxf(x, dpp_mov<0x141>(x));
    return x;
}

// ---------- merged: blocks 0..2047 BN1-stats, block 2048 QP-build ----------
// Round-15 (occupancy theory): r3/r4 proved operand-fetch style is NOT the FC
// bottleneck (s_load == LDS-broadcast, both ~8x over issue model). Common factor
// of all slow kernels: 2 waves/SIMD. BN1 grid 512 -> 2048 blocks (32 rows each,
// sX 4 KB; ~35 KB LDS -> 4 blocks/CU = 4 waves/SIMD, 2x latency hiding).
__global__ __launch_bounds__(256) void k_buildstats(const float* L, const float* LP, const float* LR,
                                                    const float* A, const float* Bm,
                                                    const float* u0, const float* s0,
                                                    const float* x, const float* w1, const float* b1,
                                                    float* ws){
    __shared__ float sL[1024], sLP[1024], sA[1024], sQ[1024], sP[1024];
    __shared__ float sPow[4][64];
    __shared__ float sBh[128*10];
    __shared__ float sQB[128*10];
    __shared__ float sR[3];
    __shared__ __align__(16) float sX[1024];   // 32 x-rows, 4 KB (BN1 path only)
    int t = threadIdx.x;
    if (blockIdx.x < 2048){
        // ---- BN1 stats path: partial col sum/sumsq into 4 spread buffers ----
        int rb = blockIdx.x >> 2;        // 512 row-groups of 32 rows
        int cb = blockIdx.x & 3;         // 4 col-groups of 256 cols
        int c = cb * 256 + t;
        const float4* wg4 = (const float4*)(w1 + (size_t)c * 32);
        float4 wr[8];
        #pragma unroll
        for (int q = 0; q < 8; ++q) wr[q] = wg4[q];
        float bc = b1[c];
        int r0 = rb * 32;
        // stage x rows r0..r0+31 (coalesced: 256 float4 over 256 threads)
        const float4* xg4 = (const float4*)x + (size_t)r0 * 8;
        float4* sX4 = (float4*)sX;
        sX4[t] = xg4[t];
        __syncthreads();
        float sum = 0.0f, sq = 0.0f;
        #pragma unroll 2
        for (int r = 0; r < 32; ++r){
            const float4* xr4 = sX4 + r * 8;   // wave-uniform -> broadcast ds_read_b128
            float a0 = 0, a1 = 0, a2 = 0, a3 = 0;
            #pragma unroll
            for (int q = 0; q < 8; ++q){
                float4 v = xr4[q];
                a0 = fmaf(v.x, wr[q].x, a0);
                a1 = fmaf(v.y, wr[q].y, a1);
                a2 = fmaf(v.z, wr[q].z, a2);
                a3 = fmaf(v.w, wr[q].w, a3);
            }
            float h = lrelu((a0 + a1) + (a2 + a3) + bc);
            sum += h; sq = fmaf(h, h, sq);
        }
        int buf = (rb & 3) * 1024 + c;
        atomicAdd(&ws[P1S_OFF + buf], sum);
        atomicAdd(&ws[P1Q_OFF + buf], sq);
        return;
    }
    // ---- QP build path (single block, blockIdx 2048) ----
    for (int idx = t; idx < 1024; idx += 256){
        int i = idx >> 5, j = idx & 31;
        sL[idx]  = (j <= i) ? L[idx]  : 0.0f;
        sLP[idx] = (j <= i) ? LP[idx] : 0.0f;
        sA[idx]  = A[idx];
    }
    if (t < 64) sPow[0][t] = Bm[t];
    if (t == 0){
        float a = LR[0], b = LR[2], c = LR[3];   // tril: [[a,0],[b,c]]
        sR[0] = a*a + EPSQ; sR[1] = a*b; sR[2] = b*b + c*c + EPSQ;
    }
    __syncthreads();
    for (int idx = t; idx < 1024; idx += 256){
        int i = idx >> 5, j = idx & 31;
        float q = 0.0f, p = 0.0f;
        for (int k = 0; k < 32; ++k){
            q = fmaf(sL[i*32+k],  sL[j*32+k],  q);
            p = fmaf(sLP[i*32+k], sLP[j*32+k], p);
        }
        if (i == j){ q += EPSQ; p += EPSQ; }
        sQ[idx] = q; sP[idx] = p;
    }
    for (int kp = 1; kp < 4; ++kp){
        __syncthreads();
        if (t < 64){
            int i = t >> 1, c = t & 1;
            float a = 0.0f;
            for (int j = 0; j < 32; ++j) a = fmaf(sA[i*32+j], sPow[kp-1][j*2+c], a);
            sPow[kp][t] = a;
        }
    }
    __syncthreads();
    for (int idx = t; idx < 1280; idx += 256){
        int r = idx / 10, c = idx % 10;
        int bi = r >> 5, ri = r & 31, bj = c >> 1, cj = c & 1;
        sBh[idx] = (bj <= bi) ? sPow[bi-bj][ri*2+cj] : 0.0f;
    }
    __syncthreads();
    for (int idx = t; idx < 1280; idx += 256){
        int r = idx / 10, c = idx % 10;
        int bi = r >> 5, ri = r & 31;
        const float* Qd = (bi < 3) ? sQ : sP;
        float a = 0.0f;
        for (int k = 0; k < 32; ++k) a = fmaf(Qd[ri*32+k], sBh[(bi*32+k)*10+c], a);
        sQB[idx] = a;
    }
    __syncthreads();
    if (t < 120){
        int i = t / 12, j = t % 12;
        float a = 0.0f;
        if (j < 10){
            for (int r = 0; r < 128; ++r) a = fmaf(sBh[r*10+i], sQB[r*10+j], a);
            if ((i >> 1) == (j >> 1)) a += sR[(i&1)+(j&1)];
        }
        ws[QM_OFF + t] = a;
    }
    for (int idx = t; idx < 144*12; idx += 256){
        int m = idx / 12, i = idx % 12;
        float v = 0.0f;
        if (i < 10 && m < MIx) v = (m < 10) ? ((i == m) ? 1.0f : 0.0f) : sBh[(m-10)*10 + i];
        ws[G_OFF + idx] = v;
    }
    for (int m = t; m < 144; m += 256){
        float hv = 0.0f;
        if (m < MIx){
            hv = s0[m];
            if (m < 10) hv += u0[m];
            else { for (int i = 0; i < 10; ++i) hv = fmaf(sBh[(m-10)*10+i], u0[i], hv); }
        }
        ws[H_OFF + m] = hv;
    }
}

// ---------- fc2 with BN1-finalize folded in-block ----------
// Round-15: 1024 threads/block (16 waves = 4 waves/SIMD, 2x latency hiding).
// Same chunk scheme as r4; each wave owns an 8-row slice of each 128-row chunk
// (klc = q*8+i, wave-uniform -> s_load/broadcast preserved). pacc = 40 KB.
__global__ __launch_bounds__(1024) void k_fc2(const float* __restrict__ x, const float* __restrict__ w1,
                                              const float* __restrict__ w2, const float* __restrict__ b1v,
                                              const float* __restrict__ b2v, const float* __restrict__ g1,
                                              const float* __restrict__ bb1, float* __restrict__ ws){
    __shared__ __align__(16) float sPool[10240];  // chunks: sW 4096 floats; after: pacc 10240
    __shared__ float sA1[1024], sC1[1024];
    int t = threadIdx.x;
    if (t < 1024){
        int k = t;
        float ssum = 0.0f, qsum = 0.0f;
        #pragma unroll
        for (int b = 0; b < 4; ++b){
            ssum += ws[P1S_OFF + b*1024 + k];
            qsum += ws[P1Q_OFF + b*1024 + k];
        }
        float mu  = ssum * (1.0f/16384.0f);
        float var = qsum * (1.0f/16384.0f) - mu*mu;
        float a1 = g1[k] / sqrtf(var + BNEPS);
        sA1[k] = a1;
        sC1[k] = bb1[k] - mu * a1;
    }
    int r = t & 63;
    int q = t >> 6;                  // 0..15: wave owns an 8-row slice of each chunk
    int row = blockIdx.x * 64 + r;
    const float4* xg4 = (const float4*)(x + (size_t)row * 32);
    float4 xr[8];
    #pragma unroll
    for (int i = 0; i < 8; ++i) xr[i] = xg4[i];
    float acc[10];
    #pragma unroll
    for (int j = 0; j < 10; ++j) acc[j] = 0.0f;
    const float4* w1g4 = (const float4*)w1;
    float4* sW4 = (float4*)sPool;
    for (int ch = 0; ch < 8; ++ch){
        __syncthreads();   // previous chunk fully consumed (also fences sA1/sC1 on ch=0)
        if (t < 1024) sW4[t] = w1g4[ch*1024 + t];
        __syncthreads();
        #pragma unroll
        for (int i = 0; i < 8; ++i){
            int klc = __builtin_amdgcn_readfirstlane(q*8 + i);       // chunk-local row
            int kl  = __builtin_amdgcn_readfirstlane(ch*128 + klc);  // global k
            const float4* wv4 = sW4 + klc*8;   // wave-uniform -> broadcast ds_read_b128
            float a0 = 0, a1 = 0, a2 = 0, a3 = 0;
            #pragma unroll
            for (int u = 0; u < 8; ++u){
                float4 wv = wv4[u];
                float4 xv = xr[u];
                a0 = fmaf(xv.x, wv.x, a0);
                a1 = fmaf(xv.y, wv.y, a1);
                a2 = fmaf(xv.z, wv.z, a2);
                a3 = fmaf(xv.w, wv.w, a3);
            }
            float h = fmaf(lrelu((a0 + a1) + (a2 + a3) + b1v[kl]), sA1[kl], sC1[kl]);
            #pragma unroll
            for (int j = 0; j < 10; ++j) acc[j] = fmaf(h, w2[j*1024 + kl], acc[j]);
        }
    }
    __syncthreads();   // all waves done with sW before pacc aliases the region
    float* pacc = sPool;
    #pragma unroll
    for (int j = 0; j < 10; ++j) pacc[t*10 + j] = acc[j];
    __syncthreads();
    if (t < 64){
        float pv[10];
        #pragma unroll
        for (int j = 0; j < 10; ++j){
            float a = b2v[j];
            #pragma unroll
            for (int w = 0; w < 16; ++w) a += pacc[(w*64 + t)*10 + j];
            pv[j] = lrelu(a);
        }
        #pragma unroll
        for (int j = 0; j < 10; ++j) ws[PRAW_OFF + (size_t)(blockIdx.x*64 + t)*10 + j] = pv[j];
        float sv[10], qv[10];
        #pragma unroll
        for (int j = 0; j < 10; ++j){ sv[j] = pv[j]; qv[j] = pv[j]*pv[j]; }
        #pragma unroll
        for (int m = 1; m < 64; m <<= 1){
            #pragma unroll
            for (int j = 0; j < 10; ++j){
                sv[j] += __shfl_xor(sv[j], m);
                qv[j] += __shfl_xor(qv[j], m);
            }
        }
        if (t == 0){
            int base = P2_OFF + (blockIdx.x & 15) * 20;
            #pragma unroll
            for (int j = 0; j < 10; ++j){
                atomicAdd(&ws[base + j], sv[j]);
                atomicAdd(&ws[base + 10 + j], qv[j]);
            }
        }
    }
}

// ---------- batched IPM: 8 lanes/element, 8 elements per 64-thread block ----------
// Round-11 structure (REVERTED round-12's register promotion: allocator hard-caps
// this kernel at 128 VGPR — promoting g6/g7/hh/isv spilled to scratch, 137 MB
// of WRITE_SIZE, +41 us. 128-VGPR envelope is the law here.)
//   16 B_hat slots paired into v2f; G pairs B=2/4/6 in registers; B=8 pairs in
//   LDS (pair-packed, stride 36); h pairs in LDS; rp in registers.
#define TIX(i,j) ((i)*((i)+1)/2 + (j))

#define PSTEPA(P, B, GP) { \
    v2f sv = s2[P], lv = lam2[P]; \
    v2f isv; isv.x = frcp(sv.x); isv.y = frcp(sv.y); \
    v2f wv = lv * isv; \
    v2f r = sv - *(const v2f*)(sHH2 + (P)*16 + lg*2); \
    _Pragma("unroll") \
    for (int _i = 0; _i < (B); ++_i) r = pkfma(splat2(z[_i]), GP[_i], r); \
    rp2[P] = r; \
    sl2 = pkfma(sv, lv, sl2); \
    _Pragma("unroll") \
    for (int _i = 0; _i < (B); ++_i){ \
        v2f wg = wv * GP[_i]; \
        _Pragma("unroll") \
        for (int _j = 0; _j <= _i; ++_j) Hm2[TIX(_i,_j)] = pkfma(wg, GP[_j], Hm2[TIX(_i,_j)]); \
    } }

#define PSTEPB(P, B, GP) { \
    v2f sv = s2[P], lv = lam2[P]; \
    v2f isv; isv.x = frcp(sv.x); isv.y = frcp(sv.y); \
    v2f coef = pkfma(lv, rp2[P], smu2) * isv; \
    _Pragma("unroll") \
    for (int _i = 0; _i < (B); ++_i) racc2[_i] = pkfma(coef, GP[_i], racc2[_i]); }

#define PSTEPC(P, B, GP) { \
    v2f dotv = splat2(0.0f); \
    _Pragma("unroll") \
    for (int _i = 0; _i < (B); ++_i) dotv = pkfma(splat2(dz[_i]), GP[_i], dotv); \
    v2f sv = s2[P], lv = lam2[P]; \
    v2f isv; isv.x = frcp(sv.x); isv.y = frcp(sv.y); \
    v2f dsv = -(rp2[P] + dotv); \
    v2f rcv = pkfma(sv, lv, nsmu2); \
    v2f dlv = -(pkfma(lv, dsv, rcv) * isv); \
    ds2[P] = dsv; dl2[P] = dlv; \
    v2f ilv; ilv.x = frcp(lv.x); ilv.y = frcp(lv.y); \
    av2 = pkmax(av2, pkmax((-dsv)*isv, (-dlv)*ilv)); }

#define LOADP(GP, PP) v2f GP[8]; { \
    const float4* _g4 = (const float4*)(sG3 + lg*36 + (PP)*16); \
    float4 _a = _g4[0], _b = _g4[1], _c = _g4[2], _d = _g4[3]; \
    GP[0] = make2(_a.x,_a.y); GP[1] = make2(_a.z,_a.w); \
    GP[2] = make2(_b.x,_b.y); GP[3] = make2(_b.z,_b.w); \
    GP[4] = make2(_c.x,_c.y); GP[5] = make2(_c.z,_c.w); \
    GP[6] = make2(_d.x,_d.y); GP[7] = make2(_d.z,_d.w); }

__global__ __launch_bounds__(64, 2) void k_ipm(const float* __restrict__ ws, const float* __restrict__ g2v,
                                               const float* __restrict__ bb2, float* __restrict__ out){
    __shared__ __align__(16) float sQm[120];
    __shared__ __align__(16) float sQt2[72];    // {Q/8, 0} interleaved, tri rows 0..7
    __shared__ __align__(16) float sPV[8*12];
    __shared__ __align__(16) float sG3[8*36];   // B=8 G pairs, pair-packed per lg
    __shared__ __align__(16) float sHH2[128];   // h pair-packed: [p*16 + lg*2 + c]
    __shared__ float sA2[10], sC2[10];
    int t = threadIdx.x;
    for (int i = t; i < 120; i += 64) sQm[i] = ws[QM_OFF + i];
    if (t < 36){
        int i = 0;
        #pragma unroll
        for (int r = 1; r < 8; ++r) if (TIX(r,0) <= t) i = r;
        int j = t - TIX(i,0);
        sQt2[t*2]   = ws[QM_OFF + i*12 + j] * 0.125f;
        sQt2[t*2+1] = 0.0f;
    }
    if (t < 10){   // BN2 finalize (redundant per block — trivial)
        float ssum = 0.0f, qsum = 0.0f;
        #pragma unroll
        for (int b = 0; b < 16; ++b){
            ssum += ws[P2_OFF + b*20 + t];
            qsum += ws[P2_OFF + b*20 + 10 + t];
        }
        float mu  = ssum * (1.0f/16384.0f);
        float var = qsum * (1.0f/16384.0f) - mu*mu;
        float a2 = g2v[t] / sqrtf(var + BNEPS);
        sA2[t] = a2;
        sC2[t] = bb2[t] - mu * a2;
    }
    __syncthreads();

    int lg = t & 7;
    int eidx = t >> 3;
    int elem = blockIdx.x * 8 + eidx;
    const float* GB = ws + G_OFF;
    const float4* sQm4 = (const float4*)sQm;

    for (int i = t; i < 80; i += 64){
        int e = i / 10, c = i - e*10;
        int el = blockIdx.x * 8 + e;
        sPV[e*12 + c] = fmaf(ws[PRAW_OFF + (size_t)el*10 + c], sA2[c], sC2[c]);
    }
    // h pair-packed: pair p covers slots 2p,2p+1 (block b=p>>1, k&3 = 2(p&1)+c)
    for (int i = t; i < 128; i += 64){
        int c = i & 1, lgx = (i >> 1) & 7, p = i >> 4;
        int row = 10 + (p >> 1)*32 + (2*(p & 1) + c)*8 + lgx;
        sHH2[p*16 + lgx*2 + c] = ws[H_OFF + row];
    }
    // B=8 pairs (slots 12..15) pair-packed in LDS: sG3[lg*36 + pp*16 + i*2 + c]
    for (int i = t; i < 256; i += 64){
        int c = i & 1, ii = (i >> 1) & 7, pp = (i >> 4) & 1, lgx = i >> 5;
        int row = 106 + (pp*2 + c)*8 + lgx;
        sG3[lgx*36 + pp*16 + ii*2 + c] = GB[row*12 + ii];
    }
    // register-resident G pairs (B=2,4,6): gp[i] = {G[row_a,i], G[row_b,i]}
    v2f g0[2], g1[2], g2r[4], g3r[4], g4r[6], g5r[6];
    {
        int ra, rb;
        ra = 10 + lg; rb = 18 + lg;
        #pragma unroll
        for (int i = 0; i < 2; ++i) g0[i] = make2(GB[ra*12+i], GB[rb*12+i]);
        ra = 26 + lg; rb = 34 + lg;
        #pragma unroll
        for (int i = 0; i < 2; ++i) g1[i] = make2(GB[ra*12+i], GB[rb*12+i]);
        ra = 42 + lg; rb = 50 + lg;
        #pragma unroll
        for (int i = 0; i < 4; ++i) g2r[i] = make2(GB[ra*12+i], GB[rb*12+i]);
        ra = 58 + lg; rb = 66 + lg;
        #pragma unroll
        for (int i = 0; i < 4; ++i) g3r[i] = make2(GB[ra*12+i], GB[rb*12+i]);
        ra = 74 + lg; rb = 82 + lg;
        #pragma unroll
        for (int i = 0; i < 6; ++i) g4r[i] = make2(GB[ra*12+i], GB[rb*12+i]);
        ra = 90 + lg; rb = 98 + lg;
        #pragma unroll
        for (int i = 0; i < 6; ++i) g5r[i] = make2(GB[ra*12+i], GB[rb*12+i]);
    }
    float h16 = ws[H_OFF + lg];                          // identity rows 0..7
    float h17 = (lg < 2) ? ws[H_OFF + 8 + lg] : 1.0f;    // identity rows 8,9
    __syncthreads();

    float z[10];
    #pragma unroll
    for (int i = 0; i < 10; ++i) z[i] = 0.0f;
    v2f s2[8], lam2[8];
    #pragma unroll
    for (int p = 0; p < 8; ++p){ s2[p] = splat2(1.0f); lam2[p] = splat2(1.0f); }
    float s16v = 1.0f, s17v = 1.0f, lam16v = 1.0f;
    float lam17v = (lg < 2) ? 1.0f : 0.0f;

    #pragma unroll 1
    for (int it = 0; it < ITERS; ++it){
        v2f Hm2[36];
        {
            const v2f* qt2 = (const v2f*)sQt2;
            #pragma unroll
            for (int i = 0; i < 36; ++i) Hm2[i] = qt2[i];   // {Q/8, 0}
        }
        v2f sl2 = splat2(0.0f);
        v2f rp2[8];
        float rp16, rp17;
        // ---- loop A: rp + Hm (paired)
        PSTEPA(0, 2, g0)  PSTEPA(1, 2, g1)
        PSTEPA(2, 4, g2r) PSTEPA(3, 4, g3r)
        PSTEPA(4, 6, g4r) PSTEPA(5, 6, g5r)
        { LOADP(gv, 0) PSTEPA(6, 8, gv) }
        { LOADP(gv, 1) PSTEPA(7, 8, gv) }
        // ---- identity slots 16 (rows 0..7) and 17 (rows 8,9 on lanes 0,1)
        float w16, w17, sl_s;
        {
            float zs = z[0];
            #pragma unroll
            for (int i = 1; i < 8; ++i) zs = (lg == i) ? z[i] : zs;
            rp16 = zs + s16v - h16;
            sl_s = s16v * lam16v;
            w16 = lam16v * frcp(s16v);
            float zs17 = (lg == 1) ? z[9] : z[8];
            rp17 = zs17 + s17v - h17;
            sl_s = fmaf(s17v, lam17v, sl_s);
            w17 = lam17v * frcp(s17v);
        }
        // ---- fold pairs -> scalar, add identity diag, DPP 8-lane all-reduce
        float Hm[55];
        #pragma unroll
        for (int i = 0; i < 36; ++i) Hm[i] = Hm2[i].x + Hm2[i].y;
        #pragma unroll
        for (int i = 0; i < 8; ++i) Hm[TIX(i,i)] += (lg == i) ? w16 : 0.0f;
        float d88 = (lg == 0) ? w17 : 0.0f;
        float d99 = (lg == 1) ? w17 : 0.0f;
        float sl = sl2.x + sl2.y + sl_s;
        #pragma unroll
        for (int i = 0; i < 36; ++i) Hm[i] = red8_add(Hm[i]);
        d88 = red8_add(d88);
        d99 = red8_add(d99);
        sl = red8_add(sl);
        float smu = SIGMA_C * sl * (1.0f/138.0f);
        __asm__ __volatile__("" ::: "memory");   // keep B=8 LDS G-rows transient
        // ---- loop B: racc = sum_k g_k*(lam_k*rp_k+smu)/s_k (paired, .x=even .y=odd)
        v2f smu2 = splat2(smu);
        v2f racc2[8];
        #pragma unroll
        for (int i = 0; i < 8; ++i) racc2[i] = splat2(0.0f);
        PSTEPB(0, 2, g0)  PSTEPB(1, 2, g1)
        PSTEPB(2, 4, g2r) PSTEPB(3, 4, g3r)
        PSTEPB(4, 6, g4r) PSTEPB(5, 6, g5r)
        { LOADP(gv, 0) PSTEPB(6, 8, gv) }
        { LOADP(gv, 1) PSTEPB(7, 8, gv) }
        float coef16 = frcp(s16v) * fmaf(lam16v, rp16, smu);
        float coef17 = frcp(s17v) * fmaf(lam17v, rp17, smu);
        coef17 = (lg < 2) ? coef17 : 0.0f;
        float rs[10];
        #pragma unroll
        for (int i = 0; i < 8; ++i){
            float v = racc2[i].x + racc2[i].y;
            v += (lg == i) ? coef16 : 0.0f;
            rs[i] = red8_add(v);
        }
        rs[8] = red8_add((lg == 0) ? coef17 : 0.0f);
        rs[9] = red8_add((lg == 1) ? coef17 : 0.0f);
        // ---- rhs = -(p + racc) - Q z (packed Q-pass); rows 8,9 of H assigned
        v2f rhs2[5];
        {
            const float4* pv4 = (const float4*)(sPV + eidx*12);
            float4 pa = pv4[0], pb = pv4[1];
            const float2* pv2 = (const float2*)(sPV + eidx*12 + 8);
            float2 pc = pv2[0];
            rhs2[0] = make2(-(pa.x + rs[0]), -(pa.y + rs[1]));
            rhs2[1] = make2(-(pa.z + rs[2]), -(pa.w + rs[3]));
            rhs2[2] = make2(-(pb.x + rs[4]), -(pb.y + rs[5]));
            rhs2[3] = make2(-(pb.z + rs[6]), -(pb.w + rs[7]));
            rhs2[4] = make2(-(pc.x + rs[8]), -(pc.y + rs[9]));
        }
        #pragma unroll
        for (int j = 0; j < 10; ++j){
            float4 qa = sQm4[j*3+0], qb = sQm4[j*3+1], qc = sQm4[j*3+2];
            v2f mz = splat2(-z[j]);
            rhs2[0] = pkfma(mz, make2(qa.x, qa.y), rhs2[0]);
            rhs2[1] = pkfma(mz, make2(qa.z, qa.w), rhs2[1]);
            rhs2[2] = pkfma(mz, make2(qb.x, qb.y), rhs2[2]);
            rhs2[3] = pkfma(mz, make2(qb.z, qb.w), rhs2[3]);
            rhs2[4] = pkfma(mz, make2(qc.x, qc.y), rhs2[4]);
            if (j >= 8){
                float q[10] = {qa.x,qa.y,qa.z,qa.w, qb.x,qb.y,qb.z,qb.w, qc.x,qc.y};
                #pragma unroll
                for (int i = 0; i <= j; ++i) Hm[TIX(j,i)] = q[i];
            }
        }
        Hm[TIX(8,8)] += d88;
        Hm[TIX(9,9)] += d99;
        float rhs[10] = {rhs2[0].x, rhs2[0].y, rhs2[1].x, rhs2[1].y, rhs2[2].x,
                         rhs2[2].y, rhs2[3].x, rhs2[3].y, rhs2[4].x, rhs2[4].y};
        // ---- Cholesky (reciprocal diag in place)
        #pragma unroll
        for (int j = 0; j < 10; ++j){
            float d = Hm[TIX(j,j)];
            #pragma unroll
            for (int k2 = 0; k2 < j; ++k2){ float v = Hm[TIX(j,k2)]; d = fmaf(-v, v, d); }
            d = fmaxf(d, 1e-30f);
            float rinv = frsq(d);
            Hm[TIX(j,j)] = rinv;
            #pragma unroll
            for (int i = j+1; i < 10; ++i){
                float v2 = Hm[TIX(i,j)];
                #pragma unroll
                for (int k2 = 0; k2 < j; ++k2) v2 = fmaf(-Hm[TIX(i,k2)], Hm[TIX(j,k2)], v2);
                Hm[TIX(i,j)] = v2 * rinv;
            }
        }
        #pragma unroll
        for (int i = 0; i < 10; ++i){
            float v2 = rhs[i];
            #pragma unroll
            for (int k2 = 0; k2 < i; ++k2) v2 = fmaf(-Hm[TIX(i,k2)], rhs[k2], v2);
            rhs[i] = v2 * Hm[TIX(i,i)];
        }
        float dz[10];
        #pragma unroll
        for (int i = 9; i >= 0; --i){
            float v2 = rhs[i];
            #pragma unroll
            for (int k2 = i+1; k2 < 10; ++k2) v2 = fmaf(-Hm[TIX(k2,i)], dz[k2], v2);
            dz[i] = v2 * Hm[TIX(i,i)];
        }
        __asm__ __volatile__("" ::: "memory");
        // ---- loop C: steps + alpha (paired; max-of-inverse-ratios)
        v2f nsmu2 = splat2(-smu);
        v2f ds2[8], dl2[8];
        v2f av2 = splat2(0.0f);
        PSTEPC(0, 2, g0)  PSTEPC(1, 2, g1)
        PSTEPC(2, 4, g2r) PSTEPC(3, 4, g3r)
        PSTEPC(4, 6, g4r) PSTEPC(5, 6, g5r)
        { LOADP(gv, 0) PSTEPC(6, 8, gv) }
        { LOADP(gv, 1) PSTEPC(7, 8, gv) }
        float ds16, dl16, ds17, dl17;
        float ainv = fmaxf(av2.x, av2.y);
        {
            float dzs = dz[0];
            #pragma unroll
            for (int i = 1; i < 8; ++i) dzs = (lg == i) ? dz[i] : dzs;
            float dsk = -rp16 - dzs;
            float isk = frcp(s16v);
            float rc = fmaf(s16v, lam16v, -smu);
            float dlk = -(rc + lam16v * dsk) * isk;
            ds16 = dsk; dl16 = dlk;
            ainv = fmaxf(ainv, fmaxf(-dsk * isk, -dlk * frcp(lam16v)));
        }
        {
            float dzs = (lg == 1) ? dz[9] : dz[8];
            bool val = lg < 2;
            float dsk = val ? (-rp17 - dzs) : 0.0f;
            float isk = frcp(s17v);
            float rc = fmaf(s17v, lam17v, -smu);
            float dlk = -(rc + lam17v * dsk) * isk;
            dlk = val ? dlk : 0.0f;
            ds17 = dsk; dl17 = dlk;
            float cand = fmaxf(-dsk * isk, -dlk * frcp(lam17v));
            ainv = fmaxf(ainv, val ? cand : 0.0f);
        }
        ainv = red8_max(ainv);
        float alpha = fminf(1.0f, 0.99f * frcp(fmaxf(ainv, 1e-30f)));
        // ---- updates (packed s/lam)
        v2f al2 = splat2(alpha);
        #pragma unroll
        for (int i = 0; i < 10; ++i) z[i] = fmaf(alpha, dz[i], z[i]);
        #pragma unroll
        for (int p = 0; p < 8; ++p){
            s2[p]   = pkfma(al2, ds2[p], s2[p]);
            lam2[p] = pkfma(al2, dl2[p], lam2[p]);
        }
        s16v   = fmaf(alpha, ds16, s16v);
        s17v   = fmaf(alpha, ds17, s17v);
        lam16v = fmaf(alpha, dl16, lam16v);
        lam17v = fmaf(alpha, dl17, lam17v);
    }
    if (lg == 0) out[elem] = z[0];
}

extern "C" void kernel_launch(void* const* d_in, const int* in_sizes, int n_in,
                              void* d_out, int out_size, void* d_ws, size_t ws_size,
                              hipStream_t stream){
    const float* x   = (const float*)d_in[0];
    const float* w1  = (const float*)d_in[1];
    const float* b1  = (const float*)d_in[2];
    const float* w2  = (const float*)d_in[3];
    const float* b2  = (const float*)d_in[4];
    const float* g1  = (const float*)d_in[5];
    const float* bb1 = (const float*)d_in[6];
    const float* g2  = (const float*)d_in[7];
    const float* bb2 = (const float*)d_in[8];
    const float* L   = (const float*)d_in[9];
    const float* LP  = (const float*)d_in[10];
    const float* LR  = (const float*)d_in[11];
    const float* A   = (const float*)d_in[12];
    const float* Bm  = (const float*)d_in[13];
    const float* u0  = (const float*)d_in[14];
    const float* s0  = (const float*)d_in[15];
    float* ws  = (float*)d_ws;
    float* out = (float*)d_out;

    // zero P2 + P1 partial accumulators (floats 2048..10560)
    hipMemsetAsync(ws + P2_OFF, 0, (P1Q_OFF + 4096 - P2_OFF) * sizeof(float), stream);
    hipLaunchKernelGGL(k_buildstats, dim3(2049), dim3(256), 0, stream,
                       L, LP, LR, A, Bm, u0, s0, x, w1, b1, ws);
    hipLaunchKernelGGL(k_fc2, dim3(256), dim3(1024), 0, stream, x, w1, w2, b1, b2, g1, bb1, ws);
    hipLaunchKernelGGL(k_ipm, dim3(2048), dim3(64), 0, stream, ws, g2, bb2, out);
}